// Round 2
// baseline (1674.047 us; speedup 1.0000x reference)
//
#include <hip/hip_runtime.h>
#include <math.h>

// Problem constants
#define NN 50000
#define EE 800000
#define HID 128
#define HEADS 4
#define CH 32
#define LAYERS 2
#define LN_EPS 1e-5f
#define SCALE 0.17677669529663687f  // 1/sqrt(32)

__device__ __forceinline__ float sanitize(float f) {
    // nan_to_num(nan=0, posinf=0, neginf=0)
    return (f == f && fabsf(f) != INFINITY) ? f : 0.0f;
}

// ---------------- CSR build ----------------

__global__ void zero_deg_kernel(int* __restrict__ deg) {
    int i = blockIdx.x * blockDim.x + threadIdx.x;
    if (i < NN) deg[i] = 0;
}

// edge_index is int32 (JAX demotes int64 without x64 mode); harness: "integer -> const int*"
__global__ void hist_kernel(const int* __restrict__ eidx, int* __restrict__ deg) {
    int e = blockIdx.x * blockDim.x + threadIdx.x;
    if (e < EE) {
        int dst = eidx[EE + e];
        atomicAdd(&deg[dst], 1);
    }
}

// Single-block scan over N elements (exclusive). Writes row_start[0..N] and cursor copy.
__global__ __launch_bounds__(1024) void scan_kernel(const int* __restrict__ deg,
                                                    int* __restrict__ row_start,
                                                    int* __restrict__ cursor) {
    __shared__ int wsum[16];
    __shared__ int carry_s;
    int tid = threadIdx.x;
    int lane = tid & 63;
    int wid = tid >> 6;
    if (tid == 0) carry_s = 0;
    __syncthreads();
    for (int base = 0; base < NN; base += 1024) {
        int i = base + tid;
        int val = (i < NN) ? deg[i] : 0;
        // inclusive wave scan
        int sc = val;
        #pragma unroll
        for (int off = 1; off < 64; off <<= 1) {
            int t = __shfl_up(sc, off, 64);
            if (lane >= off) sc += t;
        }
        if (lane == 63) wsum[wid] = sc;
        __syncthreads();
        if (wid == 0) {
            int s = (lane < 16) ? wsum[lane] : 0;
            #pragma unroll
            for (int off = 1; off < 16; off <<= 1) {
                int t = __shfl_up(s, off, 64);
                if (lane >= off) s += t;
            }
            if (lane < 16) wsum[lane] = s;
        }
        __syncthreads();
        int waveoff = (wid > 0) ? wsum[wid - 1] : 0;
        int excl = carry_s + waveoff + sc - val;
        if (i < NN) {
            row_start[i] = excl;
            cursor[i] = excl;
        }
        __syncthreads();
        if (tid == 0) carry_s += wsum[15];
        __syncthreads();
    }
    if (tid == 0) row_start[NN] = carry_s;  // == EE
}

__global__ void scatter_kernel(const int* __restrict__ eidx,
                               const float* __restrict__ ew,
                               int* __restrict__ cursor,
                               int* __restrict__ csr_src,
                               float* __restrict__ csr_w) {
    int e = blockIdx.x * blockDim.x + threadIdx.x;
    if (e < EE) {
        int dst = eidx[EE + e];
        int src = eidx[e];
        int pos = atomicAdd(&cursor[dst], 1);
        csr_src[pos] = src;
        csr_w[pos] = sanitize(ew[e]);
    }
}

// ---------------- sanitize x -> h0 ----------------

__global__ void sanitize_kernel(const float* __restrict__ x, float* __restrict__ h0) {
    int i = blockIdx.x * blockDim.x + threadIdx.x;
    if (i < NN * HID / 4) {
        float4 f = ((const float4*)x)[i];
        f.x = sanitize(f.x); f.y = sanitize(f.y); f.z = sanitize(f.z); f.w = sanitize(f.w);
        ((float4*)h0)[i] = f;
    }
}

// ---------------- fused 4-matrix GEMM: out[n,j] = sum_k h[n,k]*W[k,j] + b[j] ----------------

#define ROWS_PER_BLOCK 64

__global__ __launch_bounds__(128) void gemm_kernel(
    const float* __restrict__ hin,
    const float* __restrict__ Wq, const float* __restrict__ Wk,
    const float* __restrict__ Wv, const float* __restrict__ Wsk,
    const float* __restrict__ bq, const float* __restrict__ bk,
    const float* __restrict__ bv, const float* __restrict__ bsk,
    float* __restrict__ oq, float* __restrict__ ok,
    float* __restrict__ ov, float* __restrict__ osk)
{
    int mat = blockIdx.y;
    const float* W; const float* b; float* o;
    if (mat == 0)      { W = Wq;  b = bq;  o = oq; }
    else if (mat == 1) { W = Wk;  b = bk;  o = ok; }
    else if (mat == 2) { W = Wv;  b = bv;  o = ov; }
    else               { W = Wsk; b = bsk; o = osk; }

    int col = threadIdx.x;  // 0..127
    float w[HID];
    #pragma unroll
    for (int kk = 0; kk < HID; kk++) w[kk] = W[kk * HID + col];
    float bias = b[col];

    int row0 = blockIdx.x * ROWS_PER_BLOCK;
    int rend = row0 + ROWS_PER_BLOCK;
    if (rend > NN) rend = NN;
    for (int row = row0; row < rend; ++row) {
        const float* hr = hin + (size_t)row * HID;
        float a0 = 0.f, a1 = 0.f;
        #pragma unroll
        for (int kk = 0; kk < HID; kk += 2) {
            a0 += hr[kk] * w[kk];
            a1 += hr[kk + 1] * w[kk + 1];
        }
        o[(size_t)row * HID + col] = a0 + a1 + bias;
    }
}

// ---------------- fused aggregate + skip + LN + ReLU + residual ----------------

__device__ __forceinline__ float red16(float x) {
    #pragma unroll
    for (int off = 8; off >= 1; off >>= 1) x += __shfl_xor(x, off, 16);
    return x;
}

__device__ __forceinline__ float red64(float x) {
    #pragma unroll
    for (int off = 32; off >= 1; off >>= 1) x += __shfl_xor(x, off, 64);
    return x;
}

__global__ __launch_bounds__(256) void agg_kernel(
    const float* __restrict__ q, const float* __restrict__ k,
    const float* __restrict__ v, const float* __restrict__ skp,
    const float* __restrict__ hres,
    const float* __restrict__ We,    // [128] this layer
    const float* __restrict__ ln_g, const float* __restrict__ ln_b,  // [128] each
    const int* __restrict__ row_start,
    const int* __restrict__ csr_src, const float* __restrict__ csr_w,
    float* __restrict__ hout)
{
    int node = blockIdx.x * 4 + (threadIdx.x >> 6);
    if (node >= NN) return;
    int lane = threadIdx.x & 63;
    int c0 = lane * 2;  // two channels per lane; head = c0/32 constant within 16-lane group

    float2 q2 = *(const float2*)(q + (size_t)node * HID + c0);
    float2 we2 = *(const float2*)(We + c0);

    // per-head q . We  (folded lin_edge contribution to logits)
    float qwe = red16(q2.x * we2.x + q2.y * we2.y);

    int rs = row_start[node];
    int re = row_start[node + 1];

    float m = -INFINITY, s = 0.f, tw = 0.f;
    float accx = 0.f, accy = 0.f;

    for (int i = rs; i < re; ++i) {
        int src = csr_src[i];
        float w = csr_w[i];
        const float* kp = k + (size_t)src * HID + c0;
        const float* vp = v + (size_t)src * HID + c0;
        float2 k2 = *(const float2*)kp;
        float2 v2 = *(const float2*)vp;
        float d = red16(k2.x * q2.x + k2.y * q2.y);
        float logit = (d + w * qwe) * SCALE;
        float mn = fmaxf(m, logit);
        float corr = __expf(m - mn);
        float p = __expf(logit - mn);
        s = s * corr + p;
        tw = tw * corr + p * w;
        accx = accx * corr + p * v2.x;
        accy = accy * corr + p * v2.y;
        m = mn;
    }

    float ox = 0.f, oy = 0.f;
    if (re > rs) {
        float inv = 1.f / s;
        ox = (accx + tw * we2.x) * inv;
        oy = (accy + tw * we2.y) * inv;
    }

    float2 sk = *(const float2*)(skp + (size_t)node * HID + c0);
    ox = sanitize(ox + sk.x);
    oy = sanitize(oy + sk.y);

    // LayerNorm over 128 channels
    float mu = red64(ox + oy) * (1.f / 128.f);
    float dx = ox - mu, dy = oy - mu;
    float var = red64(dx * dx + dy * dy) * (1.f / 128.f);
    float rstd = rsqrtf(var + LN_EPS);

    float2 g = *(const float2*)(ln_g + c0);
    float2 bb = *(const float2*)(ln_b + c0);
    float rx = fmaxf(dx * rstd * g.x + bb.x, 0.f);
    float ry = fmaxf(dy * rstd * g.y + bb.y, 0.f);

    float2 hr = *(const float2*)(hres + (size_t)node * HID + c0);
    float2 outv;
    outv.x = sanitize(rx + hr.x);
    outv.y = sanitize(ry + hr.y);
    *(float2*)(hout + (size_t)node * HID + c0) = outv;
}

// ---------------- host ----------------

extern "C" void kernel_launch(void* const* d_in, const int* in_sizes, int n_in,
                              void* d_out, int out_size, void* d_ws, size_t ws_size,
                              hipStream_t stream) {
    const float* x      = (const float*)d_in[0];
    const int*   ei     = (const int*)d_in[1];   // int32! (JAX demotes int64)
    const float* ew     = (const float*)d_in[2];
    const float* Wq     = (const float*)d_in[3];
    const float* bq     = (const float*)d_in[4];
    const float* Wk     = (const float*)d_in[5];
    const float* bk     = (const float*)d_in[6];
    const float* Wv     = (const float*)d_in[7];
    const float* bv     = (const float*)d_in[8];
    const float* We     = (const float*)d_in[9];
    const float* Wsk    = (const float*)d_in[10];
    const float* bsk    = (const float*)d_in[11];
    const float* ln_g   = (const float*)d_in[12];
    const float* ln_b   = (const float*)d_in[13];

    // workspace layout
    float* ws = (float*)d_ws;
    const size_t NH = (size_t)NN * HID;
    float* q   = ws;            // 6.4M floats
    float* kk  = q + NH;
    float* vv  = kk + NH;
    float* sk  = vv + NH;
    float* h0  = sk + NH;       // sanitized x
    float* h1  = h0 + NH;       // layer-0 output
    int* deg       = (int*)(h1 + NH);
    int* row_start = deg + NN;
    int* cursor    = row_start + NN + 1;
    int* csr_src   = cursor + NN;
    float* csr_w   = (float*)(csr_src + EE);
    // total ~ 6*25.6MB + ~10MB  ≈ 164 MB

    // ---- CSR build (dst is layer-invariant) ----
    zero_deg_kernel<<<(NN + 255) / 256, 256, 0, stream>>>(deg);
    hist_kernel<<<(EE + 255) / 256, 256, 0, stream>>>(ei, deg);
    scan_kernel<<<1, 1024, 0, stream>>>(deg, row_start, cursor);
    scatter_kernel<<<(EE + 255) / 256, 256, 0, stream>>>(ei, ew, cursor, csr_src, csr_w);

    // ---- sanitize input ----
    sanitize_kernel<<<(NN * HID / 4 + 255) / 256, 256, 0, stream>>>(x, h0);

    const int WELEM = HID * HID;  // per-layer weight stride
    dim3 ggrid((NN + ROWS_PER_BLOCK - 1) / ROWS_PER_BLOCK, 4);

    for (int l = 0; l < LAYERS; ++l) {
        const float* hin = (l == 0) ? h0 : h1;
        float* hout = (l == 0) ? h1 : (float*)d_out;
        gemm_kernel<<<ggrid, 128, 0, stream>>>(
            hin,
            Wq + l * WELEM, Wk + l * WELEM, Wv + l * WELEM, Wsk + l * WELEM,
            bq + l * HID, bk + l * HID, bv + l * HID, bsk + l * HID,
            q, kk, vv, sk);
        agg_kernel<<<(NN + 3) / 4, 256, 0, stream>>>(
            q, kk, vv, sk, hin,
            We + l * HID, ln_g + l * HID, ln_b + l * HID,
            row_start, csr_src, csr_w, hout);
    }
}

// Round 5
// 658.725 us; speedup vs baseline: 2.5413x; 2.5413x over previous
//
#include <hip/hip_runtime.h>
#include <math.h>

// Problem constants
#define NN 50000
#define EE 800000
#define HID 128
#define HEADS 4
#define CH 32
#define LAYERS 2
#define LN_EPS 1e-5f
#define SCALE 0.17677669529663687f  // 1/sqrt(32)

__device__ __forceinline__ float sanitize(float f) {
    return (f == f && fabsf(f) != INFINITY) ? f : 0.0f;
}

// ---------------- CSR build ----------------

__global__ void zero_deg_kernel(int* __restrict__ deg) {
    int i = blockIdx.x * blockDim.x + threadIdx.x;
    if (i < NN) deg[i] = 0;
}

__global__ void hist_kernel(const int* __restrict__ eidx, int* __restrict__ deg) {
    int e = blockIdx.x * blockDim.x + threadIdx.x;
    if (e < EE) {
        int dst = eidx[EE + e];
        atomicAdd(&deg[dst], 1);
    }
}

__global__ __launch_bounds__(1024) void scan_kernel(const int* __restrict__ deg,
                                                    int* __restrict__ row_start,
                                                    int* __restrict__ cursor) {
    __shared__ int wsum[16];
    __shared__ int carry_s;
    int tid = threadIdx.x;
    int lane = tid & 63;
    int wid = tid >> 6;
    if (tid == 0) carry_s = 0;
    __syncthreads();
    for (int base = 0; base < NN; base += 1024) {
        int i = base + tid;
        int val = (i < NN) ? deg[i] : 0;
        int sc = val;
        #pragma unroll
        for (int off = 1; off < 64; off <<= 1) {
            int t = __shfl_up(sc, off, 64);
            if (lane >= off) sc += t;
        }
        if (lane == 63) wsum[wid] = sc;
        __syncthreads();
        if (wid == 0) {
            int s = (lane < 16) ? wsum[lane] : 0;
            #pragma unroll
            for (int off = 1; off < 16; off <<= 1) {
                int t = __shfl_up(s, off, 64);
                if (lane >= off) s += t;
            }
            if (lane < 16) wsum[lane] = s;
        }
        __syncthreads();
        int waveoff = (wid > 0) ? wsum[wid - 1] : 0;
        int excl = carry_s + waveoff + sc - val;
        if (i < NN) {
            row_start[i] = excl;
            cursor[i] = excl;
        }
        __syncthreads();
        if (tid == 0) carry_s += wsum[15];
        __syncthreads();
    }
    if (tid == 0) row_start[NN] = carry_s;
}

__global__ void scatter_kernel(const int* __restrict__ eidx,
                               const float* __restrict__ ew,
                               int* __restrict__ cursor,
                               int* __restrict__ csr_src,
                               float* __restrict__ csr_w) {
    int e = blockIdx.x * blockDim.x + threadIdx.x;
    if (e < EE) {
        int dst = eidx[EE + e];
        int src = eidx[e];
        int pos = atomicAdd(&cursor[dst], 1);
        csr_src[pos] = src;
        csr_w[pos] = sanitize(ew[e]);
    }
}

// ---------------- sanitize x -> h0 ----------------

__global__ void sanitize_kernel(const float* __restrict__ x, float* __restrict__ h0) {
    int i = blockIdx.x * blockDim.x + threadIdx.x;
    if (i < NN * HID / 4) {
        float4 f = ((const float4*)x)[i];
        f.x = sanitize(f.x); f.y = sanitize(f.y); f.z = sanitize(f.z); f.w = sanitize(f.w);
        ((float4*)h0)[i] = f;
    }
}

// ---------------- LDS-tiled GEMM: out[n,j] = sum_k h[n,k]*W[k,j] + b[j] ----------------
// Block: 256 threads. Tile: 64 rows x 128 cols, K chunked by 32.
// Thread (cg=tid&31, rg=tid>>5): 8 rows (rg*8..) x 4 cols (cg*4..), fp32 acc.
// LDS 24 KB -> ~6 blocks/CU. Inner 4-k step: 12 ds_read_b128 : 128 FMA (VALU-bound).

#define GR 64
#define GK 32

__global__ __launch_bounds__(256) void gemm_kernel(
    const float* __restrict__ hin,
    const float* __restrict__ Wq, const float* __restrict__ Wk,
    const float* __restrict__ Wv, const float* __restrict__ Wsk,
    const float* __restrict__ bq, const float* __restrict__ bk,
    const float* __restrict__ bv, const float* __restrict__ bsk,
    float* __restrict__ oq, float* __restrict__ ok,
    float* __restrict__ ov, float* __restrict__ osk)
{
    __shared__ float sh[GR][GK];    // 8 KB
    __shared__ float sw[GK][HID];   // 16 KB

    int mat = blockIdx.y;
    const float* W; const float* b; float* o;
    if (mat == 0)      { W = Wq;  b = bq;  o = oq; }
    else if (mat == 1) { W = Wk;  b = bk;  o = ok; }
    else if (mat == 2) { W = Wv;  b = bv;  o = ov; }
    else               { W = Wsk; b = bsk; o = osk; }

    const int tid = threadIdx.x;
    const int cg = tid & 31;    // cols cg*4 .. cg*4+3
    const int rg = tid >> 5;    // rows rg*8 .. rg*8+7
    const int row0 = blockIdx.x * GR;

    float4 acc[8];
    #pragma unroll
    for (int r = 0; r < 8; ++r) acc[r] = make_float4(0.f, 0.f, 0.f, 0.f);

    for (int kc = 0; kc < HID; kc += GK) {
        __syncthreads();  // protect previous chunk's LDS reads
        // stage h tile: 64 rows x 32 k = 512 float4
        #pragma unroll
        for (int p = 0; p < 2; ++p) {
            int idx = p * 256 + tid;
            int r = idx >> 3;        // 0..63
            int c4 = idx & 7;        // 0..7
            int grow = row0 + r;
            float4 hv = make_float4(0.f, 0.f, 0.f, 0.f);
            if (grow < NN) hv = *(const float4*)(hin + (size_t)grow * HID + kc + c4 * 4);
            *(float4*)(&sh[r][c4 * 4]) = hv;
        }
        // stage W chunk: rows kc..kc+31 full width = contiguous 16 KB = 1024 float4
        #pragma unroll
        for (int p = 0; p < 4; ++p) {
            int idx = p * 256 + tid;
            ((float4*)sw)[idx] = ((const float4*)(W + (size_t)kc * HID))[idx];
        }
        __syncthreads();

        #pragma unroll
        for (int k4 = 0; k4 < GK; k4 += 4) {
            float4 b0 = *(float4*)(&sw[k4 + 0][cg * 4]);
            float4 b1 = *(float4*)(&sw[k4 + 1][cg * 4]);
            float4 b2 = *(float4*)(&sw[k4 + 2][cg * 4]);
            float4 b3 = *(float4*)(&sw[k4 + 3][cg * 4]);
            #pragma unroll
            for (int rr = 0; rr < 8; ++rr) {
                float4 a = *(float4*)(&sh[rg * 8 + rr][k4]);
                float4 t = acc[rr];
                t.x = fmaf(a.x, b0.x, fmaf(a.y, b1.x, fmaf(a.z, b2.x, fmaf(a.w, b3.x, t.x))));
                t.y = fmaf(a.x, b0.y, fmaf(a.y, b1.y, fmaf(a.z, b2.y, fmaf(a.w, b3.y, t.y))));
                t.z = fmaf(a.x, b0.z, fmaf(a.y, b1.z, fmaf(a.z, b2.z, fmaf(a.w, b3.z, t.z))));
                t.w = fmaf(a.x, b0.w, fmaf(a.y, b1.w, fmaf(a.z, b2.w, fmaf(a.w, b3.w, t.w))));
                acc[rr] = t;
            }
        }
    }

    float4 bias = *(const float4*)(b + cg * 4);
    #pragma unroll
    for (int rr = 0; rr < 8; ++rr) {
        int grow = row0 + rg * 8 + rr;
        if (grow < NN) {
            float4 t = acc[rr];
            t.x += bias.x; t.y += bias.y; t.z += bias.z; t.w += bias.w;
            *(float4*)(o + (size_t)grow * HID + cg * 4) = t;
        }
    }
}

// ---------------- fused aggregate + skip + LN + ReLU + residual ----------------

__device__ __forceinline__ float red16(float x) {
    #pragma unroll
    for (int off = 8; off >= 1; off >>= 1) x += __shfl_xor(x, off, 16);
    return x;
}

__device__ __forceinline__ float red64(float x) {
    #pragma unroll
    for (int off = 32; off >= 1; off >>= 1) x += __shfl_xor(x, off, 64);
    return x;
}

__global__ __launch_bounds__(256) void agg_kernel(
    const float* __restrict__ q, const float* __restrict__ k,
    const float* __restrict__ v, const float* __restrict__ skp,
    const float* __restrict__ hres,
    const float* __restrict__ We,
    const float* __restrict__ ln_g, const float* __restrict__ ln_b,
    const int* __restrict__ row_start,
    const int* __restrict__ csr_src, const float* __restrict__ csr_w,
    float* __restrict__ hout)
{
    int node = blockIdx.x * 4 + (threadIdx.x >> 6);
    if (node >= NN) return;
    int lane = threadIdx.x & 63;
    int c0 = lane * 2;

    float2 q2 = *(const float2*)(q + (size_t)node * HID + c0);
    float2 we2 = *(const float2*)(We + c0);
    float qwe = red16(q2.x * we2.x + q2.y * we2.y);

    int rs = row_start[node];
    int re = row_start[node + 1];

    // two independent online-softmax states (ILP x2), merged at the end
    float m0 = -INFINITY, s0 = 0.f, tw0 = 0.f, ax0 = 0.f, ay0 = 0.f;
    float m1 = -INFINITY, s1 = 0.f, tw1 = 0.f, ax1 = 0.f, ay1 = 0.f;

    int i = rs;
    for (; i + 2 <= re; i += 2) {
        int sA = csr_src[i];
        int sB = csr_src[i + 1];
        float wA = csr_w[i];
        float wB = csr_w[i + 1];
        float2 kA = *(const float2*)(k + (size_t)sA * HID + c0);
        float2 kB = *(const float2*)(k + (size_t)sB * HID + c0);
        float2 vA = *(const float2*)(v + (size_t)sA * HID + c0);
        float2 vB = *(const float2*)(v + (size_t)sB * HID + c0);
        float dA = red16(kA.x * q2.x + kA.y * q2.y);
        float dB = red16(kB.x * q2.x + kB.y * q2.y);
        float lA = (dA + wA * qwe) * SCALE;
        float lB = (dB + wB * qwe) * SCALE;
        {
            float mn = fmaxf(m0, lA);
            float cr = __expf(m0 - mn);
            float p = __expf(lA - mn);
            s0 = s0 * cr + p; tw0 = tw0 * cr + p * wA;
            ax0 = ax0 * cr + p * vA.x; ay0 = ay0 * cr + p * vA.y;
            m0 = mn;
        }
        {
            float mn = fmaxf(m1, lB);
            float cr = __expf(m1 - mn);
            float p = __expf(lB - mn);
            s1 = s1 * cr + p; tw1 = tw1 * cr + p * wB;
            ax1 = ax1 * cr + p * vB.x; ay1 = ay1 * cr + p * vB.y;
            m1 = mn;
        }
    }
    if (i < re) {
        int sA = csr_src[i];
        float wA = csr_w[i];
        float2 kA = *(const float2*)(k + (size_t)sA * HID + c0);
        float2 vA = *(const float2*)(v + (size_t)sA * HID + c0);
        float dA = red16(kA.x * q2.x + kA.y * q2.y);
        float lA = (dA + wA * qwe) * SCALE;
        float mn = fmaxf(m0, lA);
        float cr = __expf(m0 - mn);
        float p = __expf(lA - mn);
        s0 = s0 * cr + p; tw0 = tw0 * cr + p * wA;
        ax0 = ax0 * cr + p * vA.x; ay0 = ay0 * cr + p * vA.y;
        m0 = mn;
    }

    float ox = 0.f, oy = 0.f;
    if (re > rs) {
        float mn = fmaxf(m0, m1);
        float c0e = (m0 == -INFINITY) ? 0.f : __expf(m0 - mn);
        float c1e = (m1 == -INFINITY) ? 0.f : __expf(m1 - mn);
        float s  = s0 * c0e + s1 * c1e;
        float tw = tw0 * c0e + tw1 * c1e;
        float ax = ax0 * c0e + ax1 * c1e;
        float ay = ay0 * c0e + ay1 * c1e;
        float inv = 1.f / s;
        ox = (ax + tw * we2.x) * inv;
        oy = (ay + tw * we2.y) * inv;
    }

    float2 sk = *(const float2*)(skp + (size_t)node * HID + c0);
    ox = sanitize(ox + sk.x);
    oy = sanitize(oy + sk.y);

    float mu = red64(ox + oy) * (1.f / 128.f);
    float dx = ox - mu, dy = oy - mu;
    float var = red64(dx * dx + dy * dy) * (1.f / 128.f);
    float rstd = rsqrtf(var + LN_EPS);

    float2 g = *(const float2*)(ln_g + c0);
    float2 bb = *(const float2*)(ln_b + c0);
    float rx = fmaxf(dx * rstd * g.x + bb.x, 0.f);
    float ry = fmaxf(dy * rstd * g.y + bb.y, 0.f);

    float2 hr = *(const float2*)(hres + (size_t)node * HID + c0);
    float2 outv;
    outv.x = sanitize(rx + hr.x);
    outv.y = sanitize(ry + hr.y);
    *(float2*)(hout + (size_t)node * HID + c0) = outv;
}

// ---------------- host ----------------

extern "C" void kernel_launch(void* const* d_in, const int* in_sizes, int n_in,
                              void* d_out, int out_size, void* d_ws, size_t ws_size,
                              hipStream_t stream) {
    const float* x      = (const float*)d_in[0];
    const int*   ei     = (const int*)d_in[1];   // int32 (JAX demotes int64)
    const float* ew     = (const float*)d_in[2];
    const float* Wq     = (const float*)d_in[3];
    const float* bq     = (const float*)d_in[4];
    const float* Wk     = (const float*)d_in[5];
    const float* bk     = (const float*)d_in[6];
    const float* Wv     = (const float*)d_in[7];
    const float* bv     = (const float*)d_in[8];
    const float* We     = (const float*)d_in[9];
    const float* Wsk    = (const float*)d_in[10];
    const float* bsk    = (const float*)d_in[11];
    const float* ln_g   = (const float*)d_in[12];
    const float* ln_b   = (const float*)d_in[13];

    float* ws = (float*)d_ws;
    const size_t NH = (size_t)NN * HID;
    float* q   = ws;
    float* kk  = q + NH;
    float* vv  = kk + NH;
    float* sk  = vv + NH;
    float* h0  = sk + NH;
    float* h1  = h0 + NH;
    int* deg       = (int*)(h1 + NH);
    int* row_start = deg + NN;
    int* cursor    = row_start + NN + 1;
    int* csr_src   = cursor + NN;
    float* csr_w   = (float*)(csr_src + EE);

    zero_deg_kernel<<<(NN + 255) / 256, 256, 0, stream>>>(deg);
    hist_kernel<<<(EE + 255) / 256, 256, 0, stream>>>(ei, deg);
    scan_kernel<<<1, 1024, 0, stream>>>(deg, row_start, cursor);
    scatter_kernel<<<(EE + 255) / 256, 256, 0, stream>>>(ei, ew, cursor, csr_src, csr_w);

    sanitize_kernel<<<(NN * HID / 4 + 255) / 256, 256, 0, stream>>>(x, h0);

    const int WELEM = HID * HID;
    dim3 ggrid((NN + GR - 1) / GR, 4);

    for (int l = 0; l < LAYERS; ++l) {
        const float* hin = (l == 0) ? h0 : h1;
        float* hout = (l == 0) ? h1 : (float*)d_out;
        gemm_kernel<<<ggrid, 256, 0, stream>>>(
            hin,
            Wq + l * WELEM, Wk + l * WELEM, Wv + l * WELEM, Wsk + l * WELEM,
            bq + l * HID, bk + l * HID, bv + l * HID, bsk + l * HID,
            q, kk, vv, sk);
        agg_kernel<<<(NN + 3) / 4, 256, 0, stream>>>(
            q, kk, vv, sk, hin,
            We + l * HID, ln_g + l * HID, ln_b + l * HID,
            row_start, csr_src, csr_w, hout);
    }
}

// Round 7
// 562.213 us; speedup vs baseline: 2.9776x; 1.1717x over previous
//
#include <hip/hip_runtime.h>
#include <hip/hip_fp16.h>
#include <math.h>

#define NN 50000
#define EE 800000
#define HID 128
#define LAYERS 2
#define LN_EPS 1e-5f
#define SCALE 0.17677669529663687f  // 1/sqrt(32)

typedef _Float16 f16x8 __attribute__((ext_vector_type(8)));
typedef float f32x4 __attribute__((ext_vector_type(4)));

__device__ __forceinline__ float sanitize(float f) {
    return (f == f && fabsf(f) != INFINITY) ? f : 0.0f;
}

// ---------------- CSR build ----------------

__global__ void zero_deg_kernel(int* __restrict__ deg) {
    int i = blockIdx.x * blockDim.x + threadIdx.x;
    if (i < NN) deg[i] = 0;
}

__global__ void hist_kernel(const int* __restrict__ eidx, int* __restrict__ deg) {
    int e = blockIdx.x * blockDim.x + threadIdx.x;
    if (e < EE) atomicAdd(&deg[eidx[EE + e]], 1);
}

__global__ __launch_bounds__(1024) void scan_kernel(const int* __restrict__ deg,
                                                    int* __restrict__ row_start,
                                                    int* __restrict__ cursor) {
    __shared__ int wsum[16];
    __shared__ int carry_s;
    int tid = threadIdx.x;
    int lane = tid & 63;
    int wid = tid >> 6;
    if (tid == 0) carry_s = 0;
    __syncthreads();
    for (int base = 0; base < NN; base += 1024) {
        int i = base + tid;
        int val = (i < NN) ? deg[i] : 0;
        int sc = val;
        #pragma unroll
        for (int off = 1; off < 64; off <<= 1) {
            int t = __shfl_up(sc, off, 64);
            if (lane >= off) sc += t;
        }
        if (lane == 63) wsum[wid] = sc;
        __syncthreads();
        if (wid == 0) {
            int s = (lane < 16) ? wsum[lane] : 0;
            #pragma unroll
            for (int off = 1; off < 16; off <<= 1) {
                int t = __shfl_up(s, off, 64);
                if (lane >= off) s += t;
            }
            if (lane < 16) wsum[lane] = s;
        }
        __syncthreads();
        int waveoff = (wid > 0) ? wsum[wid - 1] : 0;
        int excl = carry_s + waveoff + sc - val;
        if (i < NN) {
            row_start[i] = excl;
            cursor[i] = excl;
        }
        __syncthreads();
        if (tid == 0) carry_s += wsum[15];
        __syncthreads();
    }
    if (tid == 0) row_start[NN] = carry_s;
}

// packed CSR entry: low 32 = src, high 32 = weight bits (one 8B store/load per edge)
__global__ void scatter_kernel(const int* __restrict__ eidx,
                               const float* __restrict__ ew,
                               int* __restrict__ cursor,
                               long long* __restrict__ csr_pk) {
    int e = blockIdx.x * blockDim.x + threadIdx.x;
    if (e < EE) {
        int dst = eidx[EE + e];
        int src = eidx[e];
        int pos = atomicAdd(&cursor[dst], 1);
        unsigned wb = __float_as_uint(sanitize(ew[e]));
        csr_pk[pos] = ((long long)wb << 32) | (unsigned)src;
    }
}

// ---------------- sanitize x -> h0 (f32) + hh (f16) ----------------

__global__ void sanitize_kernel(const float* __restrict__ x, float* __restrict__ h0,
                                __half* __restrict__ hh) {
    int i = blockIdx.x * blockDim.x + threadIdx.x;
    if (i < NN * HID / 4) {
        float4 f = ((const float4*)x)[i];
        f.x = sanitize(f.x); f.y = sanitize(f.y); f.z = sanitize(f.z); f.w = sanitize(f.w);
        ((float4*)h0)[i] = f;
        __half2* hp = (__half2*)(hh + (size_t)i * 4);
        hp[0] = __floats2half2_rn(f.x, f.y);
        hp[1] = __floats2half2_rn(f.z, f.w);
    }
}

// ---------------- W^T f16 precompute: WT[l][m][col][k] = W[l][k][col] ----------------

__global__ void wtcvt_kernel(const float* __restrict__ Wq, const float* __restrict__ Wk,
                             const float* __restrict__ Wv, __half* __restrict__ WT) {
    int idx = blockIdx.x * blockDim.x + threadIdx.x;
    if (idx >= LAYERS * 3 * HID * HID) return;
    int k = idx & 127;
    int c = (idx >> 7) & 127;
    int lm = idx >> 14;
    int m = lm % 3;
    int l = lm / 3;
    const float* W = (m == 0) ? Wq : (m == 1) ? Wk : Wv;
    WT[idx] = __float2half(W[l * HID * HID + k * HID + c]);
}

// ---------------- fused q/k/v via fp16 MFMA ----------------
// Block 256 = 4 waves; wave w handles rows row0+w*16 .. +15, all 128 cols, 3 mats.
// A frag: lane reads hh[row0+(l&15)][k0+(l>>4)*8 .. +8] (16B). Held in regs across mats.
// B frag: lane reads WT[col0+(l&15)][k0+(l>>4)*8 .. +8] (16B), L2-resident (96KB).
// C: col = tile*16+(lane&15), row = row0+(lane>>4)*4+reg.

__global__ __launch_bounds__(256) void mfma_qkv_kernel(
    const __half* __restrict__ hh, const __half* __restrict__ WT,
    const float* __restrict__ bq, const float* __restrict__ bk, const float* __restrict__ bv,
    __half* __restrict__ qh, __half* __restrict__ kv)
{
    int wid = threadIdx.x >> 6;
    int lane = threadIdx.x & 63;
    int row0 = blockIdx.x * 64 + wid * 16;
    int arow = row0 + (lane & 15);
    if (arow >= NN) arow = NN - 1;   // clamp loads; stores guarded
    int ksub = (lane >> 4) * 8;

    const _Float16* hp = (const _Float16*)(hh + (size_t)arow * HID + ksub);
    f16x8 a0 = *(const f16x8*)(hp + 0);
    f16x8 a1 = *(const f16x8*)(hp + 32);
    f16x8 a2 = *(const f16x8*)(hp + 64);
    f16x8 a3 = *(const f16x8*)(hp + 96);

    #pragma unroll
    for (int m = 0; m < 3; ++m) {
        const _Float16* Wm = (const _Float16*)(WT + m * HID * HID);
        const float* bias = (m == 0) ? bq : (m == 1) ? bk : bv;
        #pragma unroll
        for (int t = 0; t < 8; ++t) {
            int col = t * 16 + (lane & 15);
            const _Float16* wc = Wm + (size_t)col * HID + ksub;
            f32x4 acc = {0.f, 0.f, 0.f, 0.f};
            acc = __builtin_amdgcn_mfma_f32_16x16x32_f16(a0, *(const f16x8*)(wc + 0),  acc, 0, 0, 0);
            acc = __builtin_amdgcn_mfma_f32_16x16x32_f16(a1, *(const f16x8*)(wc + 32), acc, 0, 0, 0);
            acc = __builtin_amdgcn_mfma_f32_16x16x32_f16(a2, *(const f16x8*)(wc + 64), acc, 0, 0, 0);
            acc = __builtin_amdgcn_mfma_f32_16x16x32_f16(a3, *(const f16x8*)(wc + 96), acc, 0, 0, 0);
            float bcol = bias[col];
            #pragma unroll
            for (int r = 0; r < 4; ++r) {
                int row = row0 + (lane >> 4) * 4 + r;
                if (row < NN) {
                    __half val = __float2half(acc[r] + bcol);
                    if (m == 0)      qh[(size_t)row * HID + col] = val;
                    else if (m == 1) kv[(size_t)row * 256 + col] = val;
                    else             kv[(size_t)row * 256 + 128 + col] = val;
                }
            }
        }
    }
}

// ---------------- fp32 skip GEMM (output-path precision) ----------------

#define GR 64
#define GK 32

__global__ __launch_bounds__(256) void gemm_skip_kernel(
    const float* __restrict__ hin, const float* __restrict__ W,
    const float* __restrict__ b, float* __restrict__ o)
{
    __shared__ float sh[GR][GK];
    __shared__ float sw[GK][HID];

    const int tid = threadIdx.x;
    const int cg = tid & 31;
    const int rg = tid >> 5;
    const int row0 = blockIdx.x * GR;

    float4 acc[8];
    #pragma unroll
    for (int r = 0; r < 8; ++r) acc[r] = make_float4(0.f, 0.f, 0.f, 0.f);

    for (int kc = 0; kc < HID; kc += GK) {
        __syncthreads();
        #pragma unroll
        for (int p = 0; p < 2; ++p) {
            int idx = p * 256 + tid;
            int r = idx >> 3;
            int c4 = idx & 7;
            int grow = row0 + r;
            float4 hv = make_float4(0.f, 0.f, 0.f, 0.f);
            if (grow < NN) hv = *(const float4*)(hin + (size_t)grow * HID + kc + c4 * 4);
            *(float4*)(&sh[r][c4 * 4]) = hv;
        }
        #pragma unroll
        for (int p = 0; p < 4; ++p) {
            int idx = p * 256 + tid;
            ((float4*)sw)[idx] = ((const float4*)(W + (size_t)kc * HID))[idx];
        }
        __syncthreads();

        #pragma unroll
        for (int k4 = 0; k4 < GK; k4 += 4) {
            float4 b0 = *(float4*)(&sw[k4 + 0][cg * 4]);
            float4 b1 = *(float4*)(&sw[k4 + 1][cg * 4]);
            float4 b2 = *(float4*)(&sw[k4 + 2][cg * 4]);
            float4 b3 = *(float4*)(&sw[k4 + 3][cg * 4]);
            #pragma unroll
            for (int rr = 0; rr < 8; ++rr) {
                float4 a = *(float4*)(&sh[rg * 8 + rr][k4]);
                float4 t = acc[rr];
                t.x = fmaf(a.x, b0.x, fmaf(a.y, b1.x, fmaf(a.z, b2.x, fmaf(a.w, b3.x, t.x))));
                t.y = fmaf(a.x, b0.y, fmaf(a.y, b1.y, fmaf(a.z, b2.y, fmaf(a.w, b3.y, t.y))));
                t.z = fmaf(a.x, b0.z, fmaf(a.y, b1.z, fmaf(a.z, b2.z, fmaf(a.w, b3.z, t.z))));
                t.w = fmaf(a.x, b0.w, fmaf(a.y, b1.w, fmaf(a.z, b2.w, fmaf(a.w, b3.w, t.w))));
                acc[rr] = t;
            }
        }
    }

    float4 bias = *(const float4*)(b + cg * 4);
    #pragma unroll
    for (int rr = 0; rr < 8; ++rr) {
        int grow = row0 + rg * 8 + rr;
        if (grow < NN) {
            float4 t = acc[rr];
            t.x += bias.x; t.y += bias.y; t.z += bias.z; t.w += bias.w;
            *(float4*)(o + (size_t)grow * HID + cg * 4) = t;
        }
    }
}

// ---------------- fused aggregate + skip + LN + ReLU + residual ----------------

__device__ __forceinline__ float red16(float x) {
    #pragma unroll
    for (int off = 8; off >= 1; off >>= 1) x += __shfl_xor(x, off, 16);
    return x;
}

__device__ __forceinline__ float red64(float x) {
    #pragma unroll
    for (int off = 32; off >= 1; off >>= 1) x += __shfl_xor(x, off, 64);
    return x;
}

struct OS { float m, s, tw, ax, ay; };

__device__ __forceinline__ void os_init(OS& o) {
    o.m = -INFINITY; o.s = 0.f; o.tw = 0.f; o.ax = 0.f; o.ay = 0.f;
}

__device__ __forceinline__ void os_upd(OS& o, float l, float w, float vx, float vy) {
    float mn = fmaxf(o.m, l);
    float cr = __expf(o.m - mn);   // m=-inf -> 0
    float p  = __expf(l - mn);
    o.s  = fmaf(o.s,  cr, p);
    o.tw = fmaf(o.tw, cr, p * w);
    o.ax = fmaf(o.ax, cr, p * vx);
    o.ay = fmaf(o.ay, cr, p * vy);
    o.m = mn;
}

__device__ __forceinline__ OS os_mrg(OS a, OS b) {
    float mn = fmaxf(a.m, b.m);
    if (mn == -INFINITY) return a;     // both empty (avoid exp(nan))
    float ca = __expf(a.m - mn);
    float cb = __expf(b.m - mn);
    OS r;
    r.m = mn;
    r.s  = a.s  * ca + b.s  * cb;
    r.tw = a.tw * ca + b.tw * cb;
    r.ax = a.ax * ca + b.ax * cb;
    r.ay = a.ay * ca + b.ay * cb;
    return r;
}

__device__ __forceinline__ void edge_step(const long long* __restrict__ csr_pk, int i,
                                          const __half* __restrict__ kv, int lane,
                                          float qx, float qy, float qwe, OS& st) {
    long long p = csr_pk[i];
    int src = (int)(p & 0xffffffffLL);
    float w = __uint_as_float((unsigned)((unsigned long long)p >> 32));
    const __half* kvp = kv + (size_t)src * 256;
    float2 k2 = __half22float2(*(const __half2*)(kvp + 2 * lane));
    float2 v2 = __half22float2(*(const __half2*)(kvp + 128 + 2 * lane));
    float d = red16(fmaf(k2.x, qx, k2.y * qy));
    float l = fmaf(w, qwe, d) * SCALE;
    os_upd(st, l, w, v2.x, v2.y);
}

__global__ __launch_bounds__(256) void agg_kernel(
    const __half* __restrict__ qh, const __half* __restrict__ kv,
    const float* __restrict__ skp, const float* __restrict__ hres,
    const float* __restrict__ We,
    const float* __restrict__ ln_g, const float* __restrict__ ln_b,
    const int* __restrict__ row_start, const long long* __restrict__ csr_pk,
    float* __restrict__ hout, __half* __restrict__ hh_out)
{
    int node = blockIdx.x * 4 + (threadIdx.x >> 6);
    if (node >= NN) return;
    int lane = threadIdx.x & 63;
    int c0 = lane * 2;

    float2 q2 = __half22float2(*(const __half2*)(qh + (size_t)node * HID + c0));
    float2 we2 = *(const float2*)(We + c0);
    float qwe = red16(fmaf(q2.x, we2.x, q2.y * we2.y));

    int rs = row_start[node];
    int re = row_start[node + 1];

    OS st0, st1, st2, st3;
    os_init(st0); os_init(st1); os_init(st2); os_init(st3);

    int i = rs;
    for (; i + 4 <= re; i += 4) {
        edge_step(csr_pk, i + 0, kv, lane, q2.x, q2.y, qwe, st0);
        edge_step(csr_pk, i + 1, kv, lane, q2.x, q2.y, qwe, st1);
        edge_step(csr_pk, i + 2, kv, lane, q2.x, q2.y, qwe, st2);
        edge_step(csr_pk, i + 3, kv, lane, q2.x, q2.y, qwe, st3);
    }
    for (; i < re; ++i) edge_step(csr_pk, i, kv, lane, q2.x, q2.y, qwe, st0);

    OS st = os_mrg(os_mrg(st0, st1), os_mrg(st2, st3));

    float ox = 0.f, oy = 0.f;
    if (re > rs) {
        float inv = 1.f / st.s;
        ox = fmaf(st.tw, we2.x, st.ax) * inv;
        oy = fmaf(st.tw, we2.y, st.ay) * inv;
    }

    float2 sk = *(const float2*)(skp + (size_t)node * HID + c0);
    ox = sanitize(ox + sk.x);
    oy = sanitize(oy + sk.y);

    float mu = red64(ox + oy) * (1.f / 128.f);
    float dx = ox - mu, dy = oy - mu;
    float var = red64(fmaf(dx, dx, dy * dy)) * (1.f / 128.f);
    float rstd = rsqrtf(var + LN_EPS);

    float2 g = *(const float2*)(ln_g + c0);
    float2 bb = *(const float2*)(ln_b + c0);
    float rx = fmaxf(fmaf(dx * rstd, g.x, bb.x), 0.f);
    float ry = fmaxf(fmaf(dy * rstd, g.y, bb.y), 0.f);

    float2 hr = *(const float2*)(hres + (size_t)node * HID + c0);
    float outx = sanitize(rx + hr.x);
    float outy = sanitize(ry + hr.y);
    *(float2*)(hout + (size_t)node * HID + c0) = make_float2(outx, outy);
    *(__half2*)(hh_out + (size_t)node * HID + c0) = __floats2half2_rn(outx, outy);
}

// ---------------- host ----------------

extern "C" void kernel_launch(void* const* d_in, const int* in_sizes, int n_in,
                              void* d_out, int out_size, void* d_ws, size_t ws_size,
                              hipStream_t stream) {
    const float* x      = (const float*)d_in[0];
    const int*   ei     = (const int*)d_in[1];   // int32 (JAX demotes int64)
    const float* ew     = (const float*)d_in[2];
    const float* Wq     = (const float*)d_in[3];
    const float* bq     = (const float*)d_in[4];
    const float* Wk     = (const float*)d_in[5];
    const float* bk     = (const float*)d_in[6];
    const float* Wv     = (const float*)d_in[7];
    const float* bv     = (const float*)d_in[8];
    const float* We     = (const float*)d_in[9];
    const float* Wsk    = (const float*)d_in[10];
    const float* bsk    = (const float*)d_in[11];
    const float* ln_g   = (const float*)d_in[12];
    const float* ln_b   = (const float*)d_in[13];

    const size_t NH = (size_t)NN * HID;
    float* h0 = (float*)d_ws;          // NH f32
    float* h1 = h0 + NH;               // NH f32
    float* sk = h1 + NH;               // NH f32
    __half* hh = (__half*)(sk + NH);   // NH f16
    __half* qh = hh + NH;              // NH f16
    __half* kv = qh + NH;              // 2*NH f16
    __half* WT = kv + 2 * NH;          // 2*3*128*128 f16 = 98304
    int* deg       = (int*)(WT + LAYERS * 3 * HID * HID);
    int* row_start = deg + NN;         // NN+2 (pad for 8B align below)
    int* cursor    = row_start + NN + 2;
    long long* csr_pk = (long long*)(cursor + NN);  // EE * 8B

    // ---- CSR build (layer-invariant) ----
    zero_deg_kernel<<<(NN + 255) / 256, 256, 0, stream>>>(deg);
    hist_kernel<<<(EE + 255) / 256, 256, 0, stream>>>(ei, deg);
    scan_kernel<<<1, 1024, 0, stream>>>(deg, row_start, cursor);
    scatter_kernel<<<(EE + 255) / 256, 256, 0, stream>>>(ei, ew, cursor, csr_pk);

    // ---- input sanitize + f16 copy; W^T f16 ----
    sanitize_kernel<<<(NN * HID / 4 + 255) / 256, 256, 0, stream>>>(x, h0, hh);
    wtcvt_kernel<<<(LAYERS * 3 * HID * HID + 255) / 256, 256, 0, stream>>>(Wq, Wk, Wv, WT);

    const int WELEM = HID * HID;
    const int MROWS = (NN + 63) / 64;   // 782

    for (int l = 0; l < LAYERS; ++l) {
        const float* hin = (l == 0) ? h0 : h1;
        float* hout = (l == 0) ? h1 : (float*)d_out;
        mfma_qkv_kernel<<<MROWS, 256, 0, stream>>>(
            hh, WT + (size_t)l * 3 * WELEM,
            bq + l * HID, bk + l * HID, bv + l * HID,
            qh, kv);
        gemm_skip_kernel<<<MROWS, 256, 0, stream>>>(hin, Wsk + l * WELEM, bsk + l * HID, sk);
        agg_kernel<<<(NN + 3) / 4, 256, 0, stream>>>(
            qh, kv, sk, hin,
            We + l * HID, ln_g + l * HID, ln_b + l * HID,
            row_start, csr_pk, hout, hh);
    }
}

// Round 12
// 472.760 us; speedup vs baseline: 3.5410x; 1.1892x over previous
//
#include <hip/hip_runtime.h>
#include <hip/hip_fp16.h>
#include <math.h>

#define NN 50000
#define EE 800000
#define HID 128
#define LAYERS 2
#define LN_EPS 1e-5f
#define SCALE 0.17677669529663687f  // 1/sqrt(32)
#define NB 49                        // scan blocks = ceil(NN/1024)

typedef _Float16 f16x8 __attribute__((ext_vector_type(8)));
typedef _Float16 h2 __attribute__((ext_vector_type(2)));
typedef float f32x4 __attribute__((ext_vector_type(4)));

__device__ __forceinline__ float sanitize(float f) {
    return (f == f && fabsf(f) != INFINITY) ? f : 0.0f;
}

// ---------------- CSR build ----------------

__global__ void zero_deg_kernel(int* __restrict__ deg) {
    int i = blockIdx.x * blockDim.x + threadIdx.x;
    if (i < NN) deg[i] = 0;
}

__global__ void hist_kernel(const int* __restrict__ eidx, int* __restrict__ deg) {
    int e = blockIdx.x * blockDim.x + threadIdx.x;
    if (e < EE) atomicAdd(&deg[eidx[EE + e]], 1);
}

// 3-phase scan: per-block sums -> tiny scan -> per-block local scan + offset

__global__ __launch_bounds__(1024) void deg_bsum_kernel(const int* __restrict__ deg,
                                                        int* __restrict__ bsum) {
    __shared__ int red[16];
    int tid = threadIdx.x;
    int i = blockIdx.x * 1024 + tid;
    int v = (i < NN) ? deg[i] : 0;
    #pragma unroll
    for (int off = 32; off >= 1; off >>= 1) v += __shfl_xor(v, off, 64);
    if ((tid & 63) == 0) red[tid >> 6] = v;
    __syncthreads();
    if (tid == 0) {
        int s = 0;
        #pragma unroll
        for (int w = 0; w < 16; ++w) s += red[w];
        bsum[blockIdx.x] = s;
    }
}

__global__ void bsum_scan_kernel(const int* __restrict__ bsum, int* __restrict__ boff,
                                 int* __restrict__ row_start) {
    int lane = threadIdx.x;  // 64 threads, 1 block
    int v = (lane < NB) ? bsum[lane] : 0;
    int sc = v;
    #pragma unroll
    for (int off = 1; off < 64; off <<= 1) {
        int t = __shfl_up(sc, off, 64);
        if (lane >= off) sc += t;
    }
    if (lane < NB) boff[lane] = sc - v;
    if (lane == 63) row_start[NN] = sc;  // grand total == EE
}

__global__ __launch_bounds__(1024) void deg_scan_kernel(const int* __restrict__ deg,
                                                        const int* __restrict__ boff,
                                                        int* __restrict__ row_start,
                                                        int* __restrict__ cursor) {
    __shared__ int wsum[16];
    int tid = threadIdx.x;
    int lane = tid & 63;
    int wid = tid >> 6;
    int i = blockIdx.x * 1024 + tid;
    int val = (i < NN) ? deg[i] : 0;
    int sc = val;
    #pragma unroll
    for (int off = 1; off < 64; off <<= 1) {
        int t = __shfl_up(sc, off, 64);
        if (lane >= off) sc += t;
    }
    if (lane == 63) wsum[wid] = sc;
    __syncthreads();
    if (wid == 0) {
        int s = (lane < 16) ? wsum[lane] : 0;
        #pragma unroll
        for (int off = 1; off < 16; off <<= 1) {
            int t = __shfl_up(s, off, 64);
            if (lane >= off) s += t;
        }
        if (lane < 16) wsum[lane] = s;
    }
    __syncthreads();
    int waveoff = (wid > 0) ? wsum[wid - 1] : 0;
    int excl = boff[blockIdx.x] + waveoff + sc - val;
    if (i < NN) {
        row_start[i] = excl;
        cursor[i] = excl;
    }
}

// packed CSR entry: low 32 = src, high 32 = weight bits
__global__ void scatter_kernel(const int* __restrict__ eidx,
                               const float* __restrict__ ew,
                               int* __restrict__ cursor,
                               long long* __restrict__ csr_pk) {
    int e = blockIdx.x * blockDim.x + threadIdx.x;
    if (e < EE) {
        int dst = eidx[EE + e];
        int src = eidx[e];
        int pos = atomicAdd(&cursor[dst], 1);
        unsigned wb = __float_as_uint(sanitize(ew[e]));
        csr_pk[pos] = ((long long)wb << 32) | (unsigned)src;
    }
}

// ---------------- sanitize x -> h0 (f32) + hh (f16) ----------------

__global__ void sanitize_kernel(const float* __restrict__ x, float* __restrict__ h0,
                                __half* __restrict__ hh) {
    int i = blockIdx.x * blockDim.x + threadIdx.x;
    if (i < NN * HID / 4) {
        float4 f = ((const float4*)x)[i];
        f.x = sanitize(f.x); f.y = sanitize(f.y); f.z = sanitize(f.z); f.w = sanitize(f.w);
        ((float4*)h0)[i] = f;
        __half2* hp = (__half2*)(hh + (size_t)i * 4);
        hp[0] = __floats2half2_rn(f.x, f.y);
        hp[1] = __floats2half2_rn(f.z, f.w);
    }
}

// ---------------- W^T f16 precompute: WT[l][m][col][k] = W_m[l][k][col], m=q,k,v,skip ----------------

__global__ void wtcvt_kernel(const float* __restrict__ Wq, const float* __restrict__ Wk,
                             const float* __restrict__ Wv, const float* __restrict__ Wsk,
                             __half* __restrict__ WT) {
    int idx = blockIdx.x * blockDim.x + threadIdx.x;
    if (idx >= LAYERS * 4 * HID * HID) return;
    int k = idx & 127;
    int c = (idx >> 7) & 127;
    int m = (idx >> 14) & 3;
    int l = idx >> 16;
    const float* W = (m == 0) ? Wq : (m == 1) ? Wk : (m == 2) ? Wv : Wsk;
    WT[idx] = __float2half(W[l * HID * HID + k * HID + c]);
}

// ---------------- fused q/k/v/skip via fp16 MFMA ----------------
// Block 256 = 4 waves; wave w: rows row0+w*16..+15, all 128 cols, 4 mats.
// A frag: lane reads hh[row0+(l&15)][(l>>4)*8 ..+8]; B frag from WT[col][k] (L2-resident).
// C layout: col = t*16+(lane&15), row = row0+(lane>>4)*4+reg.  (verified: passes refcheck)

__global__ __launch_bounds__(256) void mfma_qkvs_kernel(
    const __half* __restrict__ hh, const __half* __restrict__ WT,
    const float* __restrict__ bq, const float* __restrict__ bk,
    const float* __restrict__ bv, const float* __restrict__ bsk,
    __half* __restrict__ qh, __half* __restrict__ kv, float* __restrict__ skf)
{
    int wid = threadIdx.x >> 6;
    int lane = threadIdx.x & 63;
    int row0 = blockIdx.x * 64 + wid * 16;
    int arow = row0 + (lane & 15);
    if (arow >= NN) arow = NN - 1;   // clamp loads; stores guarded
    int ksub = (lane >> 4) * 8;

    const _Float16* hp = (const _Float16*)(hh + (size_t)arow * HID + ksub);
    f16x8 a0 = *(const f16x8*)(hp + 0);
    f16x8 a1 = *(const f16x8*)(hp + 32);
    f16x8 a2 = *(const f16x8*)(hp + 64);
    f16x8 a3 = *(const f16x8*)(hp + 96);

    #pragma unroll
    for (int m = 0; m < 4; ++m) {
        const _Float16* Wm = (const _Float16*)(WT + m * HID * HID);
        const float* bias = (m == 0) ? bq : (m == 1) ? bk : (m == 2) ? bv : bsk;
        #pragma unroll
        for (int t = 0; t < 8; ++t) {
            int col = t * 16 + (lane & 15);
            const _Float16* wc = Wm + (size_t)col * HID + ksub;
            f32x4 acc = {0.f, 0.f, 0.f, 0.f};
            acc = __builtin_amdgcn_mfma_f32_16x16x32_f16(a0, *(const f16x8*)(wc + 0),  acc, 0, 0, 0);
            acc = __builtin_amdgcn_mfma_f32_16x16x32_f16(a1, *(const f16x8*)(wc + 32), acc, 0, 0, 0);
            acc = __builtin_amdgcn_mfma_f32_16x16x32_f16(a2, *(const f16x8*)(wc + 64), acc, 0, 0, 0);
            acc = __builtin_amdgcn_mfma_f32_16x16x32_f16(a3, *(const f16x8*)(wc + 96), acc, 0, 0, 0);
            float bcol = bias[col];
            #pragma unroll
            for (int r = 0; r < 4; ++r) {
                int row = row0 + (lane >> 4) * 4 + r;
                if (row < NN) {
                    float val = acc[r] + bcol;
                    if (m == 0)      qh[(size_t)row * HID + col] = __float2half(val);
                    else if (m == 1) kv[(size_t)row * 256 + col] = __float2half(val);
                    else if (m == 2) kv[(size_t)row * 256 + 128 + col] = __float2half(val);
                    else             skf[(size_t)row * HID + col] = val;
                }
            }
        }
    }
}

// ---------------- fused aggregate + skip + LN + ReLU + residual ----------------
// 16 lanes per node, 8 channels per lane. Head = 4-sublane group (32 ch).

struct OS8 { float m, s, tw; float a[8]; };

__device__ __forceinline__ void os8_init(OS8& o) {
    o.m = -INFINITY; o.s = 0.f; o.tw = 0.f;
    #pragma unroll
    for (int j = 0; j < 8; ++j) o.a[j] = 0.f;
}

__device__ __forceinline__ OS8 os8_mrg(OS8 a, OS8 b) {
    float mn = fmaxf(a.m, b.m);
    if (mn == -INFINITY) return a;
    float ca = __expf(a.m - mn);
    float cb = __expf(b.m - mn);
    OS8 r;
    r.m = mn;
    r.s  = a.s  * ca + b.s  * cb;
    r.tw = a.tw * ca + b.tw * cb;
    #pragma unroll
    for (int j = 0; j < 8; ++j) r.a[j] = a.a[j] * ca + b.a[j] * cb;
    return r;
}

__device__ __forceinline__ void edge_step(long long p, const __half* __restrict__ kv, int c0,
                                          h2 q01, h2 q23, h2 q45, h2 q67, float qwe, OS8& st) {
    int src = (int)(p & 0xffffffffLL);
    float w = __uint_as_float((unsigned)((unsigned long long)p >> 32));
    const _Float16* kvp = (const _Float16*)(kv + (size_t)src * 256);
    f16x8 k8 = *(const f16x8*)(kvp + c0);
    f16x8 v8 = *(const f16x8*)(kvp + 128 + c0);
    h2 k01 = {k8[0], k8[1]}, k23 = {k8[2], k8[3]}, k45 = {k8[4], k8[5]}, k67 = {k8[6], k8[7]};
    float d = __builtin_amdgcn_fdot2(k01, q01, 0.f, false);
    d = __builtin_amdgcn_fdot2(k23, q23, d, false);
    d = __builtin_amdgcn_fdot2(k45, q45, d, false);
    d = __builtin_amdgcn_fdot2(k67, q67, d, false);
    d += __shfl_xor(d, 1, 64);   // red4 within 4-sublane head group
    d += __shfl_xor(d, 2, 64);
    float l = fmaf(w, qwe, d) * SCALE;
    float mn = fmaxf(st.m, l);
    float cr = __expf(st.m - mn);
    float pp = __expf(l - mn);
    st.s  = fmaf(st.s,  cr, pp);
    st.tw = fmaf(st.tw, cr, pp * w);
    #pragma unroll
    for (int j = 0; j < 8; ++j) st.a[j] = fmaf(st.a[j], cr, pp * (float)v8[j]);
    st.m = mn;
}

__global__ __launch_bounds__(256) void agg_kernel(
    const __half* __restrict__ qh, const __half* __restrict__ kv,
    const float* __restrict__ skp, const float* __restrict__ hres,
    const float* __restrict__ We,
    const float* __restrict__ ln_g, const float* __restrict__ ln_b,
    const int* __restrict__ row_start, const long long* __restrict__ csr_pk,
    float* __restrict__ hout, __half* __restrict__ hh_out)
{
    int node = blockIdx.x * 16 + (threadIdx.x >> 4);   // grid covers exactly NN
    int sl = threadIdx.x & 15;
    int c0 = sl * 8;

    f16x8 q8 = *(const f16x8*)((const _Float16*)qh + (size_t)node * HID + c0);
    h2 q01 = {q8[0], q8[1]}, q23 = {q8[2], q8[3]}, q45 = {q8[4], q8[5]}, q67 = {q8[6], q8[7]};

    float4 weA = *(const float4*)(We + c0);
    float4 weB = *(const float4*)(We + c0 + 4);
    float qwe = (float)q8[0] * weA.x + (float)q8[1] * weA.y + (float)q8[2] * weA.z + (float)q8[3] * weA.w
              + (float)q8[4] * weB.x + (float)q8[5] * weB.y + (float)q8[6] * weB.z + (float)q8[7] * weB.w;
    qwe += __shfl_xor(qwe, 1, 64);
    qwe += __shfl_xor(qwe, 2, 64);

    int rs = row_start[node];
    int re = row_start[node + 1];

    OS8 st0, st1, st2, st3;
    os8_init(st0); os8_init(st1); os8_init(st2); os8_init(st3);

    int i = rs;
    for (; i + 4 <= re; i += 4) {
        long long p0 = csr_pk[i + 0];
        long long p1 = csr_pk[i + 1];
        long long p2 = csr_pk[i + 2];
        long long p3 = csr_pk[i + 3];
        edge_step(p0, kv, c0, q01, q23, q45, q67, qwe, st0);
        edge_step(p1, kv, c0, q01, q23, q45, q67, qwe, st1);
        edge_step(p2, kv, c0, q01, q23, q45, q67, qwe, st2);
        edge_step(p3, kv, c0, q01, q23, q45, q67, qwe, st3);
    }
    for (; i < re; ++i) edge_step(csr_pk[i], kv, c0, q01, q23, q45, q67, qwe, st0);

    OS8 st = os8_mrg(os8_mrg(st0, st1), os8_mrg(st2, st3));

    float inv = (re > rs) ? 1.f / st.s : 0.f;
    float wef[8] = {weA.x, weA.y, weA.z, weA.w, weB.x, weB.y, weB.z, weB.w};

    float4 skA = *(const float4*)(skp + (size_t)node * HID + c0);
    float4 skB = *(const float4*)(skp + (size_t)node * HID + c0 + 4);
    float skv[8] = {skA.x, skA.y, skA.z, skA.w, skB.x, skB.y, skB.z, skB.w};

    float ox[8];
    float sum8 = 0.f;
    #pragma unroll
    for (int j = 0; j < 8; ++j) {
        float o = fmaf(st.tw, wef[j], st.a[j]) * inv;
        o = sanitize(o + skv[j]);
        ox[j] = o;
        sum8 += o;
    }

    // LayerNorm over the node's 16 lanes (128 ch)
    float mu = sum8;
    mu += __shfl_xor(mu, 1, 64); mu += __shfl_xor(mu, 2, 64);
    mu += __shfl_xor(mu, 4, 64); mu += __shfl_xor(mu, 8, 64);
    mu *= (1.f / 128.f);

    float var8 = 0.f;
    #pragma unroll
    for (int j = 0; j < 8; ++j) {
        float dx = ox[j] - mu;
        var8 = fmaf(dx, dx, var8);
    }
    float var = var8;
    var += __shfl_xor(var, 1, 64); var += __shfl_xor(var, 2, 64);
    var += __shfl_xor(var, 4, 64); var += __shfl_xor(var, 8, 64);
    var *= (1.f / 128.f);
    float rstd = rsqrtf(var + LN_EPS);

    float4 gA = *(const float4*)(ln_g + c0);
    float4 gB = *(const float4*)(ln_g + c0 + 4);
    float4 bA = *(const float4*)(ln_b + c0);
    float4 bB = *(const float4*)(ln_b + c0 + 4);
    float gv[8] = {gA.x, gA.y, gA.z, gA.w, gB.x, gB.y, gB.z, gB.w};
    float bv_[8] = {bA.x, bA.y, bA.z, bA.w, bB.x, bB.y, bB.z, bB.w};

    float4 hrA = *(const float4*)(hres + (size_t)node * HID + c0);
    float4 hrB = *(const float4*)(hres + (size_t)node * HID + c0 + 4);
    float hr[8] = {hrA.x, hrA.y, hrA.z, hrA.w, hrB.x, hrB.y, hrB.z, hrB.w};

    float outv[8];
    _Float16 outh[8];
    #pragma unroll
    for (int j = 0; j < 8; ++j) {
        float rx = fmaxf(fmaf((ox[j] - mu) * rstd, gv[j], bv_[j]), 0.f);
        float o = sanitize(rx + hr[j]);
        outv[j] = o;
        outh[j] = (_Float16)o;
    }
    float* op = hout + (size_t)node * HID + c0;
    *(float4*)(op)     = make_float4(outv[0], outv[1], outv[2], outv[3]);
    *(float4*)(op + 4) = make_float4(outv[4], outv[5], outv[6], outv[7]);
    *(f16x8*)((_Float16*)hh_out + (size_t)node * HID + c0) =
        *(f16x8*)outh;
}

// ---------------- host ----------------

extern "C" void kernel_launch(void* const* d_in, const int* in_sizes, int n_in,
                              void* d_out, int out_size, void* d_ws, size_t ws_size,
                              hipStream_t stream) {
    const float* x      = (const float*)d_in[0];
    const int*   ei     = (const int*)d_in[1];   // int32 (JAX demotes int64)
    const float* ew     = (const float*)d_in[2];
    const float* Wq     = (const float*)d_in[3];
    const float* bq     = (const float*)d_in[4];
    const float* Wk     = (const float*)d_in[5];
    const float* bk     = (const float*)d_in[6];
    const float* Wv     = (const float*)d_in[7];
    const float* bv     = (const float*)d_in[8];
    const float* We     = (const float*)d_in[9];
    const float* Wsk    = (const float*)d_in[10];
    const float* bsk    = (const float*)d_in[11];
    const float* ln_g   = (const float*)d_in[12];
    const float* ln_b   = (const float*)d_in[13];

    const size_t NH = (size_t)NN * HID;
    float* h0  = (float*)d_ws;          // NH f32
    float* h1  = h0 + NH;               // NH f32
    float* skf = h1 + NH;               // NH f32
    __half* hh = (__half*)(skf + NH);   // NH f16
    __half* qh = hh + NH;               // NH f16
    __half* kv = qh + NH;               // 2*NH f16
    __half* WT = kv + 2 * NH;           // LAYERS*4*128*128 f16 = 131072
    int* deg       = (int*)(WT + LAYERS * 4 * HID * HID);
    int* row_start = deg + NN;          // NN+2
    int* cursor    = row_start + NN + 2;
    int* bsum      = cursor + NN;       // 64
    int* boff      = bsum + 64;         // 64
    long long* csr_pk = (long long*)(boff + 64);  // EE entries

    // ---- CSR build (layer-invariant) ----
    zero_deg_kernel<<<(NN + 255) / 256, 256, 0, stream>>>(deg);
    hist_kernel<<<(EE + 255) / 256, 256, 0, stream>>>(ei, deg);
    deg_bsum_kernel<<<NB, 1024, 0, stream>>>(deg, bsum);
    bsum_scan_kernel<<<1, 64, 0, stream>>>(bsum, boff, row_start);
    deg_scan_kernel<<<NB, 1024, 0, stream>>>(deg, boff, row_start, cursor);
    scatter_kernel<<<(EE + 255) / 256, 256, 0, stream>>>(ei, ew, cursor, csr_pk);

    // ---- input sanitize + f16 copy; W^T f16 (4 mats) ----
    sanitize_kernel<<<(NN * HID / 4 + 255) / 256, 256, 0, stream>>>(x, h0, hh);
    wtcvt_kernel<<<(LAYERS * 4 * HID * HID + 255) / 256, 256, 0, stream>>>(Wq, Wk, Wv, Wsk, WT);

    const int WELEM = HID * HID;
    const int MROWS = (NN + 63) / 64;   // 782

    for (int l = 0; l < LAYERS; ++l) {
        const float* hin = (l == 0) ? h0 : h1;
        float* hout = (l == 0) ? h1 : (float*)d_out;
        mfma_qkvs_kernel<<<MROWS, 256, 0, stream>>>(
            hh, WT + (size_t)l * 4 * WELEM,
            bq + l * HID, bk + l * HID, bv + l * HID, bsk + l * HID,
            qh, kv, skf);
        agg_kernel<<<NN / 16, 256, 0, stream>>>(
            qh, kv, skf, hin,
            We + l * HID, ln_g + l * HID, ln_b + l * HID,
            row_start, csr_pk, hout, hh);
    }
}

// Round 14
// 469.651 us; speedup vs baseline: 3.5644x; 1.0066x over previous
//
#include <hip/hip_runtime.h>
#include <hip/hip_fp16.h>
#include <math.h>

#define NN 50000
#define EE 800000
#define HID 128
#define LAYERS 2
#define LN_EPS 1e-5f
#define SCALE 0.17677669529663687f  // 1/sqrt(32)
#define NB 49                        // scan blocks = ceil(NN/1024)

typedef _Float16 f16x8 __attribute__((ext_vector_type(8)));
typedef _Float16 h2 __attribute__((ext_vector_type(2)));
typedef float f32x4 __attribute__((ext_vector_type(4)));

__device__ __forceinline__ float sanitize(float f) {
    return (f == f && fabsf(f) != INFINITY) ? f : 0.0f;
}

// ---------------- CSR build ----------------

__global__ void zero_deg_kernel(int* __restrict__ deg) {
    int i = blockIdx.x * blockDim.x + threadIdx.x;
    if (i < NN) deg[i] = 0;
}

__global__ void hist_kernel(const int* __restrict__ eidx, int* __restrict__ deg) {
    int e = blockIdx.x * blockDim.x + threadIdx.x;
    if (e < EE) atomicAdd(&deg[eidx[EE + e]], 1);
}

// 3-phase scan: per-block sums -> tiny scan -> per-block local scan + offset

__global__ __launch_bounds__(1024) void deg_bsum_kernel(const int* __restrict__ deg,
                                                        int* __restrict__ bsum) {
    __shared__ int red[16];
    int tid = threadIdx.x;
    int i = blockIdx.x * 1024 + tid;
    int v = (i < NN) ? deg[i] : 0;
    #pragma unroll
    for (int off = 32; off >= 1; off >>= 1) v += __shfl_xor(v, off, 64);
    if ((tid & 63) == 0) red[tid >> 6] = v;
    __syncthreads();
    if (tid == 0) {
        int s = 0;
        #pragma unroll
        for (int w = 0; w < 16; ++w) s += red[w];
        bsum[blockIdx.x] = s;
    }
}

__global__ void bsum_scan_kernel(const int* __restrict__ bsum, int* __restrict__ boff,
                                 int* __restrict__ row_start) {
    int lane = threadIdx.x;  // 64 threads, 1 block
    int v = (lane < NB) ? bsum[lane] : 0;
    int sc = v;
    #pragma unroll
    for (int off = 1; off < 64; off <<= 1) {
        int t = __shfl_up(sc, off, 64);
        if (lane >= off) sc += t;
    }
    if (lane < NB) boff[lane] = sc - v;
    if (lane == 63) row_start[NN] = sc;  // grand total == EE
}

__global__ __launch_bounds__(1024) void deg_scan_kernel(const int* __restrict__ deg,
                                                        const int* __restrict__ boff,
                                                        int* __restrict__ row_start,
                                                        int* __restrict__ cursor) {
    __shared__ int wsum[16];
    int tid = threadIdx.x;
    int lane = tid & 63;
    int wid = tid >> 6;
    int i = blockIdx.x * 1024 + tid;
    int val = (i < NN) ? deg[i] : 0;
    int sc = val;
    #pragma unroll
    for (int off = 1; off < 64; off <<= 1) {
        int t = __shfl_up(sc, off, 64);
        if (lane >= off) sc += t;
    }
    if (lane == 63) wsum[wid] = sc;
    __syncthreads();
    if (wid == 0) {
        int s = (lane < 16) ? wsum[lane] : 0;
        #pragma unroll
        for (int off = 1; off < 16; off <<= 1) {
            int t = __shfl_up(s, off, 64);
            if (lane >= off) s += t;
        }
        if (lane < 16) wsum[lane] = s;
    }
    __syncthreads();
    int waveoff = (wid > 0) ? wsum[wid - 1] : 0;
    int excl = boff[blockIdx.x] + waveoff + sc - val;
    if (i < NN) {
        row_start[i] = excl;
        cursor[i] = excl;
    }
}

// packed CSR entry: low 32 = src, high 32 = weight bits
__global__ void scatter_kernel(const int* __restrict__ eidx,
                               const float* __restrict__ ew,
                               int* __restrict__ cursor,
                               long long* __restrict__ csr_pk) {
    int e = blockIdx.x * blockDim.x + threadIdx.x;
    if (e < EE) {
        int dst = eidx[EE + e];
        int src = eidx[e];
        int pos = atomicAdd(&cursor[dst], 1);
        unsigned wb = __float_as_uint(sanitize(ew[e]));
        csr_pk[pos] = ((long long)wb << 32) | (unsigned)src;
    }
}

// ---------------- sanitize x -> h0 (f32) + hh (f16) ----------------

__global__ void sanitize_kernel(const float* __restrict__ x, float* __restrict__ h0,
                                __half* __restrict__ hh) {
    int i = blockIdx.x * blockDim.x + threadIdx.x;
    if (i < NN * HID / 4) {
        float4 f = ((const float4*)x)[i];
        f.x = sanitize(f.x); f.y = sanitize(f.y); f.z = sanitize(f.z); f.w = sanitize(f.w);
        ((float4*)h0)[i] = f;
        __half2* hp = (__half2*)(hh + (size_t)i * 4);
        hp[0] = __floats2half2_rn(f.x, f.y);
        hp[1] = __floats2half2_rn(f.z, f.w);
    }
}

// ---------------- W^T f16 precompute: WT[l][m][col][k] = W_m[l][k][col], m=q,k,v,skip ----------------

__global__ void wtcvt_kernel(const float* __restrict__ Wq, const float* __restrict__ Wk,
                             const float* __restrict__ Wv, const float* __restrict__ Wsk,
                             __half* __restrict__ WT) {
    int idx = blockIdx.x * blockDim.x + threadIdx.x;
    if (idx >= LAYERS * 4 * HID * HID) return;
    int k = idx & 127;
    int c = (idx >> 7) & 127;
    int m = (idx >> 14) & 3;
    int l = idx >> 16;
    const float* W = (m == 0) ? Wq : (m == 1) ? Wk : (m == 2) ? Wv : Wsk;
    WT[idx] = __float2half(W[l * HID * HID + k * HID + c]);
}

// ---------------- fused q/k/v/skip via fp16 MFMA ----------------

__global__ __launch_bounds__(256) void mfma_qkvs_kernel(
    const __half* __restrict__ hh, const __half* __restrict__ WT,
    const float* __restrict__ bq, const float* __restrict__ bk,
    const float* __restrict__ bv, const float* __restrict__ bsk,
    __half* __restrict__ qh, __half* __restrict__ kv, float* __restrict__ skf)
{
    int wid = threadIdx.x >> 6;
    int lane = threadIdx.x & 63;
    int row0 = blockIdx.x * 64 + wid * 16;
    int arow = row0 + (lane & 15);
    if (arow >= NN) arow = NN - 1;   // clamp loads; stores guarded
    int ksub = (lane >> 4) * 8;

    const _Float16* hp = (const _Float16*)(hh + (size_t)arow * HID + ksub);
    f16x8 a0 = *(const f16x8*)(hp + 0);
    f16x8 a1 = *(const f16x8*)(hp + 32);
    f16x8 a2 = *(const f16x8*)(hp + 64);
    f16x8 a3 = *(const f16x8*)(hp + 96);

    #pragma unroll
    for (int m = 0; m < 4; ++m) {
        const _Float16* Wm = (const _Float16*)(WT + m * HID * HID);
        const float* bias = (m == 0) ? bq : (m == 1) ? bk : (m == 2) ? bv : bsk;
        #pragma unroll
        for (int t = 0; t < 8; ++t) {
            int col = t * 16 + (lane & 15);
            const _Float16* wc = Wm + (size_t)col * HID + ksub;
            f32x4 acc = {0.f, 0.f, 0.f, 0.f};
            acc = __builtin_amdgcn_mfma_f32_16x16x32_f16(a0, *(const f16x8*)(wc + 0),  acc, 0, 0, 0);
            acc = __builtin_amdgcn_mfma_f32_16x16x32_f16(a1, *(const f16x8*)(wc + 32), acc, 0, 0, 0);
            acc = __builtin_amdgcn_mfma_f32_16x16x32_f16(a2, *(const f16x8*)(wc + 64), acc, 0, 0, 0);
            acc = __builtin_amdgcn_mfma_f32_16x16x32_f16(a3, *(const f16x8*)(wc + 96), acc, 0, 0, 0);
            float bcol = bias[col];
            #pragma unroll
            for (int r = 0; r < 4; ++r) {
                int row = row0 + (lane >> 4) * 4 + r;
                if (row < NN) {
                    float val = acc[r] + bcol;
                    if (m == 0)      qh[(size_t)row * HID + col] = __float2half(val);
                    else if (m == 1) kv[(size_t)row * 256 + col] = __float2half(val);
                    else if (m == 2) kv[(size_t)row * 256 + 128 + col] = __float2half(val);
                    else             skf[(size_t)row * HID + col] = val;
                }
            }
        }
    }
}

// ---------------- fused aggregate + skip + LN + ReLU + residual ----------------
// ONE NODE PER WAVE: 4 groups of 16 lanes each take stride-4 slices of the
// node's edge list (2 independent softmax chains per group = 8 chains/node),
// merged at the end via shfl_xor(16/32). 16 lanes cover 128 ch (8 ch/lane).

struct OS8 { float m, s, tw; float a[8]; };

__device__ __forceinline__ void os8_init(OS8& o) {
    o.m = -INFINITY; o.s = 0.f; o.tw = 0.f;
    #pragma unroll
    for (int j = 0; j < 8; ++j) o.a[j] = 0.f;
}

__device__ __forceinline__ OS8 os8_mrg(OS8 a, OS8 b) {
    float mn = fmaxf(a.m, b.m);
    if (mn == -INFINITY) return a;
    float ca = __expf(a.m - mn);
    float cb = __expf(b.m - mn);
    OS8 r;
    r.m = mn;
    r.s  = a.s  * ca + b.s  * cb;
    r.tw = a.tw * ca + b.tw * cb;
    #pragma unroll
    for (int j = 0; j < 8; ++j) r.a[j] = a.a[j] * ca + b.a[j] * cb;
    return r;
}

__device__ __forceinline__ OS8 os8_shfl_xor(const OS8& o, int mask) {
    OS8 r;
    r.m  = __shfl_xor(o.m,  mask, 64);
    r.s  = __shfl_xor(o.s,  mask, 64);
    r.tw = __shfl_xor(o.tw, mask, 64);
    #pragma unroll
    for (int j = 0; j < 8; ++j) r.a[j] = __shfl_xor(o.a[j], mask, 64);
    return r;
}

__device__ __forceinline__ void edge_step(long long p, const __half* __restrict__ kv, int c0,
                                          h2 q01, h2 q23, h2 q45, h2 q67, float qwe, OS8& st) {
    int src = (int)(p & 0xffffffffLL);
    float w = __uint_as_float((unsigned)((unsigned long long)p >> 32));
    const _Float16* kvp = (const _Float16*)(kv + (size_t)src * 256);
    f16x8 k8 = *(const f16x8*)(kvp + c0);
    f16x8 v8 = *(const f16x8*)(kvp + 128 + c0);
    h2 k01 = {k8[0], k8[1]}, k23 = {k8[2], k8[3]}, k45 = {k8[4], k8[5]}, k67 = {k8[6], k8[7]};
    float d = __builtin_amdgcn_fdot2(k01, q01, 0.f, false);
    d = __builtin_amdgcn_fdot2(k23, q23, d, false);
    d = __builtin_amdgcn_fdot2(k45, q45, d, false);
    d = __builtin_amdgcn_fdot2(k67, q67, d, false);
    d += __shfl_xor(d, 1, 64);   // red4 within 4-sublane head group
    d += __shfl_xor(d, 2, 64);
    float l = fmaf(w, qwe, d) * SCALE;
    float mn = fmaxf(st.m, l);
    float cr = __expf(st.m - mn);
    float pp = __expf(l - mn);
    st.s  = fmaf(st.s,  cr, pp);
    st.tw = fmaf(st.tw, cr, pp * w);
    #pragma unroll
    for (int j = 0; j < 8; ++j) st.a[j] = fmaf(st.a[j], cr, pp * (float)v8[j]);
    st.m = mn;
}

__global__ __launch_bounds__(256) void agg_kernel(
    const __half* __restrict__ qh, const __half* __restrict__ kv,
    const float* __restrict__ skp, const float* __restrict__ hres,
    const float* __restrict__ We,
    const float* __restrict__ ln_g, const float* __restrict__ ln_b,
    const int* __restrict__ row_start, const long long* __restrict__ csr_pk,
    float* __restrict__ hout, __half* __restrict__ hh_out)
{
    int node = blockIdx.x * 4 + (threadIdx.x >> 6);   // one node per wave; grid = NN/4
    int lane = threadIdx.x & 63;
    int grp = lane >> 4;      // 0..3 edge-slice group
    int sl = lane & 15;
    int c0 = sl * 8;

    f16x8 q8 = *(const f16x8*)((const _Float16*)qh + (size_t)node * HID + c0);
    h2 q01 = {q8[0], q8[1]}, q23 = {q8[2], q8[3]}, q45 = {q8[4], q8[5]}, q67 = {q8[6], q8[7]};

    float4 weA = *(const float4*)(We + c0);
    float4 weB = *(const float4*)(We + c0 + 4);
    float qwe = (float)q8[0] * weA.x + (float)q8[1] * weA.y + (float)q8[2] * weA.z + (float)q8[3] * weA.w
              + (float)q8[4] * weB.x + (float)q8[5] * weB.y + (float)q8[6] * weB.z + (float)q8[7] * weB.w;
    qwe += __shfl_xor(qwe, 1, 64);
    qwe += __shfl_xor(qwe, 2, 64);

    int rs = row_start[node];
    int re = row_start[node + 1];

    OS8 s0, s1;
    os8_init(s0); os8_init(s1);

    // group g handles edges rs+g, rs+g+4, rs+g+8, ... (2-unrolled)
    int i = rs + grp;
    for (; i + 4 < re; i += 8) {
        long long p0 = csr_pk[i];
        long long p1 = csr_pk[i + 4];
        edge_step(p0, kv, c0, q01, q23, q45, q67, qwe, s0);
        edge_step(p1, kv, c0, q01, q23, q45, q67, qwe, s1);
    }
    if (i < re) edge_step(csr_pk[i], kv, c0, q01, q23, q45, q67, qwe, s0);

    OS8 st = os8_mrg(s0, s1);
    // cross-group merge: all lanes end with the full-node state
    st = os8_mrg(st, os8_shfl_xor(st, 16));
    st = os8_mrg(st, os8_shfl_xor(st, 32));

    float inv = (re > rs) ? 1.f / st.s : 0.f;
    float wef[8] = {weA.x, weA.y, weA.z, weA.w, weB.x, weB.y, weB.z, weB.w};

    float4 skA = *(const float4*)(skp + (size_t)node * HID + c0);
    float4 skB = *(const float4*)(skp + (size_t)node * HID + c0 + 4);
    float skv[8] = {skA.x, skA.y, skA.z, skA.w, skB.x, skB.y, skB.z, skB.w};

    float ox[8];
    float sum8 = 0.f;
    #pragma unroll
    for (int j = 0; j < 8; ++j) {
        float o = fmaf(st.tw, wef[j], st.a[j]) * inv;
        o = sanitize(o + skv[j]);
        ox[j] = o;
        sum8 += o;
    }

    // LayerNorm over 16 lanes (128 ch); groups hold identical copies
    float mu = sum8;
    mu += __shfl_xor(mu, 1, 64); mu += __shfl_xor(mu, 2, 64);
    mu += __shfl_xor(mu, 4, 64); mu += __shfl_xor(mu, 8, 64);
    mu *= (1.f / 128.f);

    float var8 = 0.f;
    #pragma unroll
    for (int j = 0; j < 8; ++j) {
        float dx = ox[j] - mu;
        var8 = fmaf(dx, dx, var8);
    }
    float var = var8;
    var += __shfl_xor(var, 1, 64); var += __shfl_xor(var, 2, 64);
    var += __shfl_xor(var, 4, 64); var += __shfl_xor(var, 8, 64);
    var *= (1.f / 128.f);
    float rstd = rsqrtf(var + LN_EPS);

    if (grp == 0) {   // one group writes; others hold duplicates
        float4 gA = *(const float4*)(ln_g + c0);
        float4 gB = *(const float4*)(ln_g + c0 + 4);
        float4 bA = *(const float4*)(ln_b + c0);
        float4 bB = *(const float4*)(ln_b + c0 + 4);
        float gv[8] = {gA.x, gA.y, gA.z, gA.w, gB.x, gB.y, gB.z, gB.w};
        float bv_[8] = {bA.x, bA.y, bA.z, bA.w, bB.x, bB.y, bB.z, bB.w};

        float4 hrA = *(const float4*)(hres + (size_t)node * HID + c0);
        float4 hrB = *(const float4*)(hres + (size_t)node * HID + c0 + 4);
        float hr[8] = {hrA.x, hrA.y, hrA.z, hrA.w, hrB.x, hrB.y, hrB.z, hrB.w};

        float outv[8];
        _Float16 outh[8];
        #pragma unroll
        for (int j = 0; j < 8; ++j) {
            float rx = fmaxf(fmaf((ox[j] - mu) * rstd, gv[j], bv_[j]), 0.f);
            float o = sanitize(rx + hr[j]);
            outv[j] = o;
            outh[j] = (_Float16)o;
        }
        float* op = hout + (size_t)node * HID + c0;
        *(float4*)(op)     = make_float4(outv[0], outv[1], outv[2], outv[3]);
        *(float4*)(op + 4) = make_float4(outv[4], outv[5], outv[6], outv[7]);
        *(f16x8*)((_Float16*)hh_out + (size_t)node * HID + c0) = *(f16x8*)outh;
    }
}

// ---------------- host ----------------

extern "C" void kernel_launch(void* const* d_in, const int* in_sizes, int n_in,
                              void* d_out, int out_size, void* d_ws, size_t ws_size,
                              hipStream_t stream) {
    const float* x      = (const float*)d_in[0];
    const int*   ei     = (const int*)d_in[1];   // int32 (JAX demotes int64)
    const float* ew     = (const float*)d_in[2];
    const float* Wq     = (const float*)d_in[3];
    const float* bq     = (const float*)d_in[4];
    const float* Wk     = (const float*)d_in[5];
    const float* bk     = (const float*)d_in[6];
    const float* Wv     = (const float*)d_in[7];
    const float* bv     = (const float*)d_in[8];
    const float* We     = (const float*)d_in[9];
    const float* Wsk    = (const float*)d_in[10];
    const float* bsk    = (const float*)d_in[11];
    const float* ln_g   = (const float*)d_in[12];
    const float* ln_b   = (const float*)d_in[13];

    const size_t NH = (size_t)NN * HID;
    float* h0  = (float*)d_ws;          // NH f32
    float* h1  = h0 + NH;               // NH f32
    float* skf = h1 + NH;               // NH f32
    __half* hh = (__half*)(skf + NH);   // NH f16
    __half* qh = hh + NH;               // NH f16
    __half* kv = qh + NH;               // 2*NH f16
    __half* WT = kv + 2 * NH;           // LAYERS*4*128*128 f16 = 131072
    int* deg       = (int*)(WT + LAYERS * 4 * HID * HID);
    int* row_start = deg + NN;          // NN+2
    int* cursor    = row_start + NN + 2;
    int* bsum      = cursor + NN;       // 64
    int* boff      = bsum + 64;         // 64
    long long* csr_pk = (long long*)(boff + 64);  // EE entries

    // ---- CSR build (layer-invariant) ----
    zero_deg_kernel<<<(NN + 255) / 256, 256, 0, stream>>>(deg);
    hist_kernel<<<(EE + 255) / 256, 256, 0, stream>>>(ei, deg);
    deg_bsum_kernel<<<NB, 1024, 0, stream>>>(deg, bsum);
    bsum_scan_kernel<<<1, 64, 0, stream>>>(bsum, boff, row_start);
    deg_scan_kernel<<<NB, 1024, 0, stream>>>(deg, boff, row_start, cursor);
    scatter_kernel<<<(EE + 255) / 256, 256, 0, stream>>>(ei, ew, cursor, csr_pk);

    // ---- input sanitize + f16 copy; W^T f16 (4 mats) ----
    sanitize_kernel<<<(NN * HID / 4 + 255) / 256, 256, 0, stream>>>(x, h0, hh);
    wtcvt_kernel<<<(LAYERS * 4 * HID * HID + 255) / 256, 256, 0, stream>>>(Wq, Wk, Wv, Wsk, WT);

    const int WELEM = HID * HID;
    const int MROWS = (NN + 63) / 64;   // 782

    for (int l = 0; l < LAYERS; ++l) {
        const float* hin = (l == 0) ? h0 : h1;
        float* hout = (l == 0) ? h1 : (float*)d_out;
        mfma_qkvs_kernel<<<MROWS, 256, 0, stream>>>(
            hh, WT + (size_t)l * 4 * WELEM,
            bq + l * HID, bk + l * HID, bv + l * HID, bsk + l * HID,
            qh, kv, skf);
        agg_kernel<<<NN / 4, 256, 0, stream>>>(
            qh, kv, skf, hin,
            We + l * HID, ln_g + l * HID, ln_b + l * HID,
            row_start, csr_pk, hout, hh);
    }
}

// Round 15
// 459.906 us; speedup vs baseline: 3.6400x; 1.0212x over previous
//
#include <hip/hip_runtime.h>
#include <hip/hip_fp16.h>
#include <math.h>

#define NN 50000
#define EE 800000
#define HID 128
#define LAYERS 2
#define LN_EPS 1e-5f
#define SCALE 0.17677669529663687f  // 1/sqrt(32)
#define NB 49                        // scan blocks = ceil(NN/1024)

typedef _Float16 f16x8 __attribute__((ext_vector_type(8)));
typedef _Float16 h2 __attribute__((ext_vector_type(2)));
typedef float f32x4 __attribute__((ext_vector_type(4)));

__device__ __forceinline__ float sanitize(float f) {
    return (f == f && fabsf(f) != INFINITY) ? f : 0.0f;
}

// ---------------- CSR build ----------------

__global__ void zero_deg_kernel(int* __restrict__ deg) {
    int i = blockIdx.x * blockDim.x + threadIdx.x;
    if (i < NN) deg[i] = 0;
}

__global__ void hist_kernel(const int* __restrict__ eidx, int* __restrict__ deg) {
    int e = blockIdx.x * blockDim.x + threadIdx.x;
    if (e < EE) atomicAdd(&deg[eidx[EE + e]], 1);
}

// 3-phase scan: per-block sums -> tiny scan -> per-block local scan + offset

__global__ __launch_bounds__(1024) void deg_bsum_kernel(const int* __restrict__ deg,
                                                        int* __restrict__ bsum) {
    __shared__ int red[16];
    int tid = threadIdx.x;
    int i = blockIdx.x * 1024 + tid;
    int v = (i < NN) ? deg[i] : 0;
    #pragma unroll
    for (int off = 32; off >= 1; off >>= 1) v += __shfl_xor(v, off, 64);
    if ((tid & 63) == 0) red[tid >> 6] = v;
    __syncthreads();
    if (tid == 0) {
        int s = 0;
        #pragma unroll
        for (int w = 0; w < 16; ++w) s += red[w];
        bsum[blockIdx.x] = s;
    }
}

__global__ void bsum_scan_kernel(const int* __restrict__ bsum, int* __restrict__ boff,
                                 int* __restrict__ row_start) {
    int lane = threadIdx.x;  // 64 threads, 1 block
    int v = (lane < NB) ? bsum[lane] : 0;
    int sc = v;
    #pragma unroll
    for (int off = 1; off < 64; off <<= 1) {
        int t = __shfl_up(sc, off, 64);
        if (lane >= off) sc += t;
    }
    if (lane < NB) boff[lane] = sc - v;
    if (lane == 63) row_start[NN] = sc;  // grand total == EE
}

__global__ __launch_bounds__(1024) void deg_scan_kernel(const int* __restrict__ deg,
                                                        const int* __restrict__ boff,
                                                        int* __restrict__ row_start,
                                                        int* __restrict__ cursor) {
    __shared__ int wsum[16];
    int tid = threadIdx.x;
    int lane = tid & 63;
    int wid = tid >> 6;
    int i = blockIdx.x * 1024 + tid;
    int val = (i < NN) ? deg[i] : 0;
    int sc = val;
    #pragma unroll
    for (int off = 1; off < 64; off <<= 1) {
        int t = __shfl_up(sc, off, 64);
        if (lane >= off) sc += t;
    }
    if (lane == 63) wsum[wid] = sc;
    __syncthreads();
    if (wid == 0) {
        int s = (lane < 16) ? wsum[lane] : 0;
        #pragma unroll
        for (int off = 1; off < 16; off <<= 1) {
            int t = __shfl_up(s, off, 64);
            if (lane >= off) s += t;
        }
        if (lane < 16) wsum[lane] = s;
    }
    __syncthreads();
    int waveoff = (wid > 0) ? wsum[wid - 1] : 0;
    int excl = boff[blockIdx.x] + waveoff + sc - val;
    if (i < NN) {
        row_start[i] = excl;
        cursor[i] = excl;
    }
}

// packed CSR entry: low 32 = src, high 32 = weight bits
__global__ void scatter_kernel(const int* __restrict__ eidx,
                               const float* __restrict__ ew,
                               int* __restrict__ cursor,
                               long long* __restrict__ csr_pk) {
    int e = blockIdx.x * blockDim.x + threadIdx.x;
    if (e < EE) {
        int dst = eidx[EE + e];
        int src = eidx[e];
        int pos = atomicAdd(&cursor[dst], 1);
        unsigned wb = __float_as_uint(sanitize(ew[e]));
        csr_pk[pos] = ((long long)wb << 32) | (unsigned)src;
    }
}

// ---------------- sanitize x -> h0 (f32) + hh (f16) ----------------

__global__ void sanitize_kernel(const float* __restrict__ x, float* __restrict__ h0,
                                __half* __restrict__ hh) {
    int i = blockIdx.x * blockDim.x + threadIdx.x;
    if (i < NN * HID / 4) {
        float4 f = ((const float4*)x)[i];
        f.x = sanitize(f.x); f.y = sanitize(f.y); f.z = sanitize(f.z); f.w = sanitize(f.w);
        ((float4*)h0)[i] = f;
        __half2* hp = (__half2*)(hh + (size_t)i * 4);
        hp[0] = __floats2half2_rn(f.x, f.y);
        hp[1] = __floats2half2_rn(f.z, f.w);
    }
}

// ---------------- W^T f16 precompute: WT[l][m][col][k] = W_m[l][k][col], m=q,k,v,skip ----------------

__global__ void wtcvt_kernel(const float* __restrict__ Wq, const float* __restrict__ Wk,
                             const float* __restrict__ Wv, const float* __restrict__ Wsk,
                             __half* __restrict__ WT) {
    int idx = blockIdx.x * blockDim.x + threadIdx.x;
    if (idx >= LAYERS * 4 * HID * HID) return;
    int k = idx & 127;
    int c = (idx >> 7) & 127;
    int m = (idx >> 14) & 3;
    int l = idx >> 16;
    const float* W = (m == 0) ? Wq : (m == 1) ? Wk : (m == 2) ? Wv : Wsk;
    WT[idx] = __float2half(W[l * HID * HID + k * HID + c]);
}

// ---------------- fused q/k/v/skip via fp16 MFMA, LDS-staged coalesced stores ----------------
// Block 256 = 4 waves; wave w: rows row0+w*16..+15 (16x128 C-tile), 4 mats.
// Epilogue: stage C-tile in wave-private LDS, write back as f16x8 (16B/lane,
// 256B..4KB contiguous segments) instead of scalar 2B scatter stores.

__global__ __launch_bounds__(256) void mfma_qkvs_kernel(
    const __half* __restrict__ hh, const __half* __restrict__ WT,
    const float* __restrict__ bq, const float* __restrict__ bk,
    const float* __restrict__ bv, const float* __restrict__ bsk,
    __half* __restrict__ qh, __half* __restrict__ kv, __half* __restrict__ skf)
{
    __shared__ _Float16 stg[4][16][HID];   // 16 KB, wave-private slices

    int wid = threadIdx.x >> 6;
    int lane = threadIdx.x & 63;
    int row0 = blockIdx.x * 64 + wid * 16;
    int arow = row0 + (lane & 15);
    if (arow >= NN) arow = NN - 1;   // clamp loads; stores guarded per wave
    int ksub = (lane >> 4) * 8;

    const _Float16* hp = (const _Float16*)(hh + (size_t)arow * HID + ksub);
    f16x8 a0 = *(const f16x8*)(hp + 0);
    f16x8 a1 = *(const f16x8*)(hp + 32);
    f16x8 a2 = *(const f16x8*)(hp + 64);
    f16x8 a3 = *(const f16x8*)(hp + 96);

    #pragma unroll
    for (int m = 0; m < 4; ++m) {
        const _Float16* Wm = (const _Float16*)(WT + m * HID * HID);
        const float* bias = (m == 0) ? bq : (m == 1) ? bk : (m == 2) ? bv : bsk;
        #pragma unroll
        for (int t = 0; t < 8; ++t) {
            int col = t * 16 + (lane & 15);
            const _Float16* wc = Wm + (size_t)col * HID + ksub;
            f32x4 acc = {0.f, 0.f, 0.f, 0.f};
            acc = __builtin_amdgcn_mfma_f32_16x16x32_f16(a0, *(const f16x8*)(wc + 0),  acc, 0, 0, 0);
            acc = __builtin_amdgcn_mfma_f32_16x16x32_f16(a1, *(const f16x8*)(wc + 32), acc, 0, 0, 0);
            acc = __builtin_amdgcn_mfma_f32_16x16x32_f16(a2, *(const f16x8*)(wc + 64), acc, 0, 0, 0);
            acc = __builtin_amdgcn_mfma_f32_16x16x32_f16(a3, *(const f16x8*)(wc + 96), acc, 0, 0, 0);
            float bcol = bias[col];
            #pragma unroll
            for (int r = 0; r < 4; ++r) {
                stg[wid][(lane >> 4) * 4 + r][col] = (_Float16)(acc[r] + bcol);
            }
        }
        // coalesced writeback of the wave's 16x128 tile (NN % 16 == 0)
        if (row0 < NN) {
            const _Float16* s = &stg[wid][0][0];
            if (m == 0 || m == 3) {
                _Float16* dst = (_Float16*)(m == 0 ? qh : skf) + (size_t)row0 * HID;
                #pragma unroll
                for (int p = 0; p < 4; ++p) {
                    int idx = p * 64 + lane;           // 256 chunks of 8 halves
                    *(f16x8*)(dst + idx * 8) = *(const f16x8*)(s + idx * 8);
                }
            } else {
                _Float16* base = (_Float16*)kv + (size_t)row0 * 256 + (m == 1 ? 0 : 128);
                #pragma unroll
                for (int p = 0; p < 4; ++p) {
                    int idx = p * 64 + lane;
                    int r = idx >> 4;                  // 0..15
                    int c8 = (idx & 15) * 8;
                    *(f16x8*)(base + (size_t)r * 256 + c8) = *(const f16x8*)(s + r * HID + c8);
                }
            }
        }
    }
}

// ---------------- fused aggregate + skip + LN + ReLU + residual ----------------
// ONE NODE PER WAVE: 4 groups of 16 lanes each take stride-4 slices of the
// node's edge list (2 independent softmax chains per group = 8 chains/node),
// merged at the end via shfl_xor(16/32). 16 lanes cover 128 ch (8 ch/lane).

struct OS8 { float m, s, tw; float a[8]; };

__device__ __forceinline__ void os8_init(OS8& o) {
    o.m = -INFINITY; o.s = 0.f; o.tw = 0.f;
    #pragma unroll
    for (int j = 0; j < 8; ++j) o.a[j] = 0.f;
}

__device__ __forceinline__ OS8 os8_mrg(OS8 a, OS8 b) {
    float mn = fmaxf(a.m, b.m);
    if (mn == -INFINITY) return a;
    float ca = __expf(a.m - mn);
    float cb = __expf(b.m - mn);
    OS8 r;
    r.m = mn;
    r.s  = a.s  * ca + b.s  * cb;
    r.tw = a.tw * ca + b.tw * cb;
    #pragma unroll
    for (int j = 0; j < 8; ++j) r.a[j] = a.a[j] * ca + b.a[j] * cb;
    return r;
}

__device__ __forceinline__ OS8 os8_shfl_xor(const OS8& o, int mask) {
    OS8 r;
    r.m  = __shfl_xor(o.m,  mask, 64);
    r.s  = __shfl_xor(o.s,  mask, 64);
    r.tw = __shfl_xor(o.tw, mask, 64);
    #pragma unroll
    for (int j = 0; j < 8; ++j) r.a[j] = __shfl_xor(o.a[j], mask, 64);
    return r;
}

__device__ __forceinline__ void edge_step(long long p, const __half* __restrict__ kv, int c0,
                                          h2 q01, h2 q23, h2 q45, h2 q67, float qwe, OS8& st) {
    int src = (int)(p & 0xffffffffLL);
    float w = __uint_as_float((unsigned)((unsigned long long)p >> 32));
    const _Float16* kvp = (const _Float16*)(kv + (size_t)src * 256);
    f16x8 k8 = *(const f16x8*)(kvp + c0);
    f16x8 v8 = *(const f16x8*)(kvp + 128 + c0);
    h2 k01 = {k8[0], k8[1]}, k23 = {k8[2], k8[3]}, k45 = {k8[4], k8[5]}, k67 = {k8[6], k8[7]};
    float d = __builtin_amdgcn_fdot2(k01, q01, 0.f, false);
    d = __builtin_amdgcn_fdot2(k23, q23, d, false);
    d = __builtin_amdgcn_fdot2(k45, q45, d, false);
    d = __builtin_amdgcn_fdot2(k67, q67, d, false);
    d += __shfl_xor(d, 1, 64);   // red4 within 4-sublane head group
    d += __shfl_xor(d, 2, 64);
    float l = fmaf(w, qwe, d) * SCALE;
    float mn = fmaxf(st.m, l);
    float cr = __expf(st.m - mn);
    float pp = __expf(l - mn);
    st.s  = fmaf(st.s,  cr, pp);
    st.tw = fmaf(st.tw, cr, pp * w);
    #pragma unroll
    for (int j = 0; j < 8; ++j) st.a[j] = fmaf(st.a[j], cr, pp * (float)v8[j]);
    st.m = mn;
}

__global__ __launch_bounds__(256) void agg_kernel(
    const __half* __restrict__ qh, const __half* __restrict__ kv,
    const __half* __restrict__ skp, const float* __restrict__ hres,
    const float* __restrict__ We,
    const float* __restrict__ ln_g, const float* __restrict__ ln_b,
    const int* __restrict__ row_start, const long long* __restrict__ csr_pk,
    float* __restrict__ hout, __half* __restrict__ hh_out)
{
    int node = blockIdx.x * 4 + (threadIdx.x >> 6);   // one node per wave; grid = NN/4
    int lane = threadIdx.x & 63;
    int grp = lane >> 4;      // 0..3 edge-slice group
    int sl = lane & 15;
    int c0 = sl * 8;

    f16x8 q8 = *(const f16x8*)((const _Float16*)qh + (size_t)node * HID + c0);
    h2 q01 = {q8[0], q8[1]}, q23 = {q8[2], q8[3]}, q45 = {q8[4], q8[5]}, q67 = {q8[6], q8[7]};

    float4 weA = *(const float4*)(We + c0);
    float4 weB = *(const float4*)(We + c0 + 4);
    float qwe = (float)q8[0] * weA.x + (float)q8[1] * weA.y + (float)q8[2] * weA.z + (float)q8[3] * weA.w
              + (float)q8[4] * weB.x + (float)q8[5] * weB.y + (float)q8[6] * weB.z + (float)q8[7] * weB.w;
    qwe += __shfl_xor(qwe, 1, 64);
    qwe += __shfl_xor(qwe, 2, 64);

    int rs = row_start[node];
    int re = row_start[node + 1];

    OS8 s0, s1;
    os8_init(s0); os8_init(s1);

    // group g handles edges rs+g, rs+g+4, rs+g+8, ... (2-unrolled)
    int i = rs + grp;
    for (; i + 4 < re; i += 8) {
        long long p0 = csr_pk[i];
        long long p1 = csr_pk[i + 4];
        edge_step(p0, kv, c0, q01, q23, q45, q67, qwe, s0);
        edge_step(p1, kv, c0, q01, q23, q45, q67, qwe, s1);
    }
    if (i < re) edge_step(csr_pk[i], kv, c0, q01, q23, q45, q67, qwe, s0);

    OS8 st = os8_mrg(s0, s1);
    // cross-group merge: all lanes end with the full-node state
    st = os8_mrg(st, os8_shfl_xor(st, 16));
    st = os8_mrg(st, os8_shfl_xor(st, 32));

    float inv = (re > rs) ? 1.f / st.s : 0.f;
    float wef[8] = {weA.x, weA.y, weA.z, weA.w, weB.x, weB.y, weB.z, weB.w};

    f16x8 sk8 = *(const f16x8*)((const _Float16*)skp + (size_t)node * HID + c0);

    float ox[8];
    float sum8 = 0.f;
    #pragma unroll
    for (int j = 0; j < 8; ++j) {
        float o = fmaf(st.tw, wef[j], st.a[j]) * inv;
        o = sanitize(o + (float)sk8[j]);
        ox[j] = o;
        sum8 += o;
    }

    // LayerNorm over 16 lanes (128 ch); groups hold identical copies
    float mu = sum8;
    mu += __shfl_xor(mu, 1, 64); mu += __shfl_xor(mu, 2, 64);
    mu += __shfl_xor(mu, 4, 64); mu += __shfl_xor(mu, 8, 64);
    mu *= (1.f / 128.f);

    float var8 = 0.f;
    #pragma unroll
    for (int j = 0; j < 8; ++j) {
        float dx = ox[j] - mu;
        var8 = fmaf(dx, dx, var8);
    }
    float var = var8;
    var += __shfl_xor(var, 1, 64); var += __shfl_xor(var, 2, 64);
    var += __shfl_xor(var, 4, 64); var += __shfl_xor(var, 8, 64);
    var *= (1.f / 128.f);
    float rstd = rsqrtf(var + LN_EPS);

    if (grp == 0) {   // one group writes; others hold duplicates
        float4 gA = *(const float4*)(ln_g + c0);
        float4 gB = *(const float4*)(ln_g + c0 + 4);
        float4 bA = *(const float4*)(ln_b + c0);
        float4 bB = *(const float4*)(ln_b + c0 + 4);
        float gv[8] = {gA.x, gA.y, gA.z, gA.w, gB.x, gB.y, gB.z, gB.w};
        float bv_[8] = {bA.x, bA.y, bA.z, bA.w, bB.x, bB.y, bB.z, bB.w};

        float4 hrA = *(const float4*)(hres + (size_t)node * HID + c0);
        float4 hrB = *(const float4*)(hres + (size_t)node * HID + c0 + 4);
        float hr[8] = {hrA.x, hrA.y, hrA.z, hrA.w, hrB.x, hrB.y, hrB.z, hrB.w};

        float outv[8];
        _Float16 outh[8];
        #pragma unroll
        for (int j = 0; j < 8; ++j) {
            float rx = fmaxf(fmaf((ox[j] - mu) * rstd, gv[j], bv_[j]), 0.f);
            float o = sanitize(rx + hr[j]);
            outv[j] = o;
            outh[j] = (_Float16)o;
        }
        float* op = hout + (size_t)node * HID + c0;
        *(float4*)(op)     = make_float4(outv[0], outv[1], outv[2], outv[3]);
        *(float4*)(op + 4) = make_float4(outv[4], outv[5], outv[6], outv[7]);
        *(f16x8*)((_Float16*)hh_out + (size_t)node * HID + c0) = *(f16x8*)outh;
    }
}

// ---------------- host ----------------

extern "C" void kernel_launch(void* const* d_in, const int* in_sizes, int n_in,
                              void* d_out, int out_size, void* d_ws, size_t ws_size,
                              hipStream_t stream) {
    const float* x      = (const float*)d_in[0];
    const int*   ei     = (const int*)d_in[1];   // int32 (JAX demotes int64)
    const float* ew     = (const float*)d_in[2];
    const float* Wq     = (const float*)d_in[3];
    const float* bq     = (const float*)d_in[4];
    const float* Wk     = (const float*)d_in[5];
    const float* bk     = (const float*)d_in[6];
    const float* Wv     = (const float*)d_in[7];
    const float* bv     = (const float*)d_in[8];
    const float* We     = (const float*)d_in[9];
    const float* Wsk    = (const float*)d_in[10];
    const float* bsk    = (const float*)d_in[11];
    const float* ln_g   = (const float*)d_in[12];
    const float* ln_b   = (const float*)d_in[13];

    const size_t NH = (size_t)NN * HID;
    float* h0  = (float*)d_ws;          // NH f32
    float* h1  = h0 + NH;               // NH f32
    __half* skf = (__half*)(h1 + NH);   // NH f16 (skip, was f32)
    __half* hh = skf + NH;              // NH f16
    __half* qh = hh + NH;               // NH f16
    __half* kv = qh + NH;               // 2*NH f16
    __half* WT = kv + 2 * NH;           // LAYERS*4*128*128 f16 = 131072
    int* deg       = (int*)(WT + LAYERS * 4 * HID * HID);
    int* row_start = deg + NN;          // NN+2
    int* cursor    = row_start + NN + 2;
    int* bsum      = cursor + NN;       // 64
    int* boff      = bsum + 64;         // 64
    long long* csr_pk = (long long*)(boff + 64);  // EE entries

    // ---- CSR build (layer-invariant) ----
    zero_deg_kernel<<<(NN + 255) / 256, 256, 0, stream>>>(deg);
    hist_kernel<<<(EE + 255) / 256, 256, 0, stream>>>(ei, deg);
    deg_bsum_kernel<<<NB, 1024, 0, stream>>>(deg, bsum);
    bsum_scan_kernel<<<1, 64, 0, stream>>>(bsum, boff, row_start);
    deg_scan_kernel<<<NB, 1024, 0, stream>>>(deg, boff, row_start, cursor);
    scatter_kernel<<<(EE + 255) / 256, 256, 0, stream>>>(ei, ew, cursor, csr_pk);

    // ---- input sanitize + f16 copy; W^T f16 (4 mats) ----
    sanitize_kernel<<<(NN * HID / 4 + 255) / 256, 256, 0, stream>>>(x, h0, hh);
    wtcvt_kernel<<<(LAYERS * 4 * HID * HID + 255) / 256, 256, 0, stream>>>(Wq, Wk, Wv, Wsk, WT);

    const int WELEM = HID * HID;
    const int MROWS = (NN + 63) / 64;   // 782

    for (int l = 0; l < LAYERS; ++l) {
        const float* hin = (l == 0) ? h0 : h1;
        float* hout = (l == 0) ? h1 : (float*)d_out;
        mfma_qkvs_kernel<<<MROWS, 256, 0, stream>>>(
            hh, WT + (size_t)l * 4 * WELEM,
            bq + l * HID, bk + l * HID, bv + l * HID, bsk + l * HID,
            qh, kv, skf);
        agg_kernel<<<NN / 4, 256, 0, stream>>>(
            qh, kv, skf, hin,
            We + l * HID, ln_g + l * HID, ln_b + l * HID,
            row_start, csr_pk, hout, hh);
    }
}